// Round 7
// baseline (1169.643 us; speedup 1.0000x reference)
//
#include <hip/hip_runtime.h>

#define NH 128
#define LAYERS 4
#define BW 128          // nodes per CSR bucket (power of 2)

typedef __attribute__((ext_vector_type(8))) short short8;
typedef __attribute__((ext_vector_type(4))) float f32x4;

__device__ __forceinline__ unsigned short f2bf(float f) {
    unsigned u = __float_as_uint(f);
    u += 0x7fffu + ((u >> 16) & 1u);          // round-to-nearest-even
    return (unsigned short)(u >> 16);
}
__device__ __forceinline__ float bflo(unsigned u) { return __uint_as_float(u << 16); }
__device__ __forceinline__ float bfhi(unsigned u) { return __uint_as_float(u & 0xffff0000u); }
__device__ __forceinline__ unsigned packbf(float x, float y) {
    return (unsigned)f2bf(x) | ((unsigned)f2bf(y) << 16);
}

// ---------------- bucket histogram + gstart boundary detection ----------------
__global__ void bcnt_gstart_kernel(const int* __restrict__ dst, int* __restrict__ bcnt, int E,
                                   const int* __restrict__ batch, int* __restrict__ gstart,
                                   int N, int G) {
    int i = blockIdx.x * blockDim.x + threadIdx.x;
    if (i < E) atomicAdd(&bcnt[dst[i] >> 7], 1);
    if (i < N) {
        int b = batch[i];
        int prev = (i == 0) ? -1 : batch[i - 1];
        for (int g = prev + 1; g <= b; ++g) gstart[g] = i;
        if (i == N - 1)
            for (int g = b + 1; g <= G; ++g) gstart[g] = N;
    }
}

// ---------------- single-block scan of bucket counts (nb <= 1024) --------------------
__global__ __launch_bounds__(1024) void bscan_kernel(const int* __restrict__ bcnt,
                                                     int* __restrict__ bktOff,
                                                     int* __restrict__ bcur, int nb) {
    __shared__ int part[1024];
    int t = threadIdx.x;
    int v = (t < nb) ? bcnt[t] : 0;
    part[t] = v;
    __syncthreads();
    for (int off = 1; off < 1024; off <<= 1) {
        int u = (t >= off) ? part[t - off] : 0;
        __syncthreads();
        part[t] += u;
        __syncthreads();
    }
    int excl = part[t] - v;
    if (t < nb) { bktOff[t] = excl; bcur[t] = excl; }
    if (t == 1023) bktOff[nb] = part[1023];
}

// ---------------- scatter edges into coarse buckets (line-filling appends) -----------
__global__ void bscatter_kernel(const int* __restrict__ src, const int* __restrict__ dst,
                                int* __restrict__ bcur, int2* __restrict__ bkt, int E) {
    int e = blockIdx.x * blockDim.x + threadIdx.x;
    if (e < E) {
        int d = dst[e];
        int p = atomicAdd(&bcur[d >> 7], 1);
        bkt[p] = make_int2(src[e], ((d & (BW - 1)) << 25) | e);   // E < 2^25
    }
}

// ---------------- per-bucket finalize: row_start slice + ordered pk ------------------
__global__ __launch_bounds__(256) void bfinal_kernel(const int2* __restrict__ bkt,
                                                     const int* __restrict__ bktOff,
                                                     int* __restrict__ row_start,
                                                     int2* __restrict__ pk,
                                                     int N, int E, int nb) {
    __shared__ int cnt[BW], par[BW];
    int b = blockIdx.x, t = threadIdx.x;
    int s = bktOff[b], e = bktOff[b + 1];
    if (t < BW) cnt[t] = 0;
    __syncthreads();
    for (int p = s + t; p < e; p += 256)
        atomicAdd(&cnt[(unsigned)bkt[p].y >> 25], 1);
    __syncthreads();
    if (t < BW) par[t] = cnt[t];
    __syncthreads();
    for (int off = 1; off < BW; off <<= 1) {
        int u = (t < BW && t >= off) ? par[t - off] : 0;
        __syncthreads();
        if (t < BW) par[t] += u;
        __syncthreads();
    }
    int node = b * BW + t;
    if (t < BW) {
        int excl = par[t] - cnt[t];
        if (node <= N) row_start[node] = s + excl;
        cnt[t] = s + excl;            // becomes the local cursor
    }
    if (b == 0 && t == 0) row_start[N] = E;
    __syncthreads();
    for (int p = s + t; p < e; p += 256) {
        int2 v = bkt[p];
        int dloc = (unsigned)v.y >> 25;
        int pos = atomicAdd(&cnt[dloc], 1);
        pk[pos] = make_int2(v.x, v.y & 0x1FFFFFF);
    }
}

// ---------------- easum[n][k] = sum over in-edges of edge_attr[e][k] -----------------
__global__ __launch_bounds__(256) void easum_kernel(const float* __restrict__ edge_attr,
                                                    const int2* __restrict__ pk,
                                                    const int* __restrict__ row_start,
                                                    float* __restrict__ easum, int N) {
    int t = threadIdx.x;
    int node = blockIdx.x * 16 + (t >> 4);
    int k = t & 15;
    if (node >= N) return;
    int rs = row_start[node], re = row_start[node + 1];
    float acc = 0.f;
    for (int p = rs; p < re; ++p)
        acc += edge_attr[(size_t)pk[p].y * 16 + k];
    easum[node * 16 + k] = acc;
}

// ---------------- aggregate: xbf = bf16( h_self + sum_in h[src] + easum@We + deg*be )
__global__ __launch_bounds__(256) void aggregate_kernel(
    const unsigned* __restrict__ hbfu, const int2* __restrict__ pk,
    const int* __restrict__ row_start, const float* __restrict__ easum,
    const float* __restrict__ We, const float* __restrict__ be,
    unsigned* __restrict__ xbfu, int N) {
    __shared__ float2 WeL[16 * 64];
    int t = threadIdx.x;
    const float2* Wg2 = (const float2*)We;
    for (int i = t; i < 16 * 64; i += 256) WeL[i] = Wg2[i];
    __syncthreads();

    int wave = t >> 6, lane = t & 63;
    int n = blockIdx.x * 4 + wave;
    if (n >= N) return;
    unsigned uself = hbfu[(size_t)n * 64 + lane];
    float2 acc = make_float2(bflo(uself), bfhi(uself));
    float2 acc2 = make_float2(0.f, 0.f);
    float2 acc3 = make_float2(0.f, 0.f);
    float2 acc4 = make_float2(0.f, 0.f);
    int rs = row_start[n], re = row_start[n + 1];
    float myea = (lane < 16) ? easum[n * 16 + lane] : 0.f;

    for (int base = rs; base < re; base += 64) {
        int cnt = min(64, re - base);
        int myS = (base + lane < re) ? pk[base + lane].x : 0;
        int j = 0;
        for (; j + 15 < cnt; j += 16) {
            int s0 = __shfl(myS, j);      int s1 = __shfl(myS, j + 1);
            int s2 = __shfl(myS, j + 2);  int s3 = __shfl(myS, j + 3);
            int s4 = __shfl(myS, j + 4);  int s5 = __shfl(myS, j + 5);
            int s6 = __shfl(myS, j + 6);  int s7 = __shfl(myS, j + 7);
            int s8 = __shfl(myS, j + 8);  int s9 = __shfl(myS, j + 9);
            int sa = __shfl(myS, j + 10); int sb = __shfl(myS, j + 11);
            int sc = __shfl(myS, j + 12); int sd = __shfl(myS, j + 13);
            int se = __shfl(myS, j + 14); int sf = __shfl(myS, j + 15);
            unsigned u0 = hbfu[(size_t)s0 * 64 + lane];
            unsigned u1 = hbfu[(size_t)s1 * 64 + lane];
            unsigned u2 = hbfu[(size_t)s2 * 64 + lane];
            unsigned u3 = hbfu[(size_t)s3 * 64 + lane];
            unsigned u4 = hbfu[(size_t)s4 * 64 + lane];
            unsigned u5 = hbfu[(size_t)s5 * 64 + lane];
            unsigned u6 = hbfu[(size_t)s6 * 64 + lane];
            unsigned u7 = hbfu[(size_t)s7 * 64 + lane];
            unsigned u8 = hbfu[(size_t)s8 * 64 + lane];
            unsigned u9 = hbfu[(size_t)s9 * 64 + lane];
            unsigned ua = hbfu[(size_t)sa * 64 + lane];
            unsigned ub = hbfu[(size_t)sb * 64 + lane];
            unsigned uc = hbfu[(size_t)sc * 64 + lane];
            unsigned ud = hbfu[(size_t)sd * 64 + lane];
            unsigned ue = hbfu[(size_t)se * 64 + lane];
            unsigned uf = hbfu[(size_t)sf * 64 + lane];
            acc.x  += bflo(u0) + bflo(u1) + bflo(u2) + bflo(u3);
            acc.y  += bfhi(u0) + bfhi(u1) + bfhi(u2) + bfhi(u3);
            acc2.x += bflo(u4) + bflo(u5) + bflo(u6) + bflo(u7);
            acc2.y += bfhi(u4) + bfhi(u5) + bfhi(u6) + bfhi(u7);
            acc3.x += bflo(u8) + bflo(u9) + bflo(ua) + bflo(ub);
            acc3.y += bfhi(u8) + bfhi(u9) + bfhi(ua) + bfhi(ub);
            acc4.x += bflo(uc) + bflo(ud) + bflo(ue) + bflo(uf);
            acc4.y += bfhi(uc) + bfhi(ud) + bfhi(ue) + bfhi(uf);
        }
        for (; j + 3 < cnt; j += 4) {
            int s0 = __shfl(myS, j);
            int s1 = __shfl(myS, j + 1);
            int s2 = __shfl(myS, j + 2);
            int s3 = __shfl(myS, j + 3);
            unsigned u0 = hbfu[(size_t)s0 * 64 + lane];
            unsigned u1 = hbfu[(size_t)s1 * 64 + lane];
            unsigned u2 = hbfu[(size_t)s2 * 64 + lane];
            unsigned u3 = hbfu[(size_t)s3 * 64 + lane];
            acc.x += bflo(u0) + bflo(u1) + bflo(u2) + bflo(u3);
            acc.y += bfhi(u0) + bfhi(u1) + bfhi(u2) + bfhi(u3);
        }
        for (; j < cnt; ++j) {
            int s = __shfl(myS, j);
            unsigned u = hbfu[(size_t)s * 64 + lane];
            acc.x += bflo(u);
            acc.y += bfhi(u);
        }
    }
    acc.x += (acc2.x + acc3.x) + acc4.x;
    acc.y += (acc2.y + acc3.y) + acc4.y;

    float degf = (float)(re - rs);
    float2 be2 = ((const float2*)be)[lane];
#pragma unroll
    for (int k = 0; k < 16; ++k) {
        float e = __shfl(myea, k);
        float2 w = WeL[k * 64 + lane];
        acc.x = fmaf(e, w.x, acc.x);
        acc.y = fmaf(e, w.y, acc.y);
    }
    acc.x += degf * be2.x;
    acc.y += degf * be2.y;
    xbfu[(size_t)n * 64 + lane] = packbf(acc.x, acc.y);
}

// ---------------- MFMA GEMM: Z = A @ W + b ------------------------------------------
// A: bf16 [N][128] (Abf) or fp32 (Af32, embed layer). W fp32 -> bf16 swizzled LDS.
// 256 thr = 4 waves; wave handles 32 rows x 128 cols = 2x8 tiles of 16x16, K=128.
// A-frag layout: m=lane&15, k=quad*8+j. B-frag: n=lane&15, k=quad*8+j.
// D layout: col=lane&15, row=quad*4+reg  (m89-verified).
__global__ __launch_bounds__(256) void gemm_mfma_kernel(
    const unsigned short* __restrict__ Abf, const float* __restrict__ Af32,
    const float* __restrict__ W, const float* __restrict__ bias,
    float* __restrict__ Zf, unsigned short* __restrict__ Zbf,
    int N, float* __restrict__ bnsum, float* __restrict__ bnsumsq) {
    __shared__ unsigned short Wl[128 * 128];   // 32KB, swizzled [nt][kc][quad][ln*8+j]
    __shared__ float bnL[2 * NH];
    int t = threadIdx.x;
    for (int i = t; i < 128 * 64; i += 256) {   // 8192 float2 of W
        float2 w2 = ((const float2*)W)[i];
        int k = i >> 6, n = (i & 63) * 2;
        int kc = k >> 5, quad = (k >> 3) & 3, j = k & 7;
        int base = (((n >> 4) * 4 + kc) * 4 + quad) * 128 + j;
        Wl[base + ((n & 15) << 3)] = f2bf(w2.x);
        Wl[base + (((n + 1) & 15) << 3)] = f2bf(w2.y);
    }
    if (t < 2 * NH) bnL[t] = 0.f;
    __syncthreads();

    int wave = t >> 6, lane = t & 63;
    int quad = lane >> 4, ln = lane & 15;
    int row0 = blockIdx.x * 128 + wave * 32;

    f32x4 acc[2][8];
#pragma unroll
    for (int nt = 0; nt < 8; ++nt) {
        float bv = bias[nt * 16 + ln];
        acc[0][nt] = (f32x4){bv, bv, bv, bv};
        acc[1][nt] = (f32x4){bv, bv, bv, bv};
    }

    for (int kc = 0; kc < 4; ++kc) {
        short8 afr[2];
        if (Af32) {
#pragma unroll
            for (int mt = 0; mt < 2; ++mt) {
                int ar = row0 + mt * 16 + ln; if (ar >= N) ar = N - 1;
                const float4* ap = (const float4*)(Af32 + (size_t)ar * NH + kc * 32 + quad * 8);
                float4 a0 = ap[0], a1 = ap[1];
                short8 v;
                v[0] = (short)f2bf(a0.x); v[1] = (short)f2bf(a0.y);
                v[2] = (short)f2bf(a0.z); v[3] = (short)f2bf(a0.w);
                v[4] = (short)f2bf(a1.x); v[5] = (short)f2bf(a1.y);
                v[6] = (short)f2bf(a1.z); v[7] = (short)f2bf(a1.w);
                afr[mt] = v;
            }
        } else {
#pragma unroll
            for (int mt = 0; mt < 2; ++mt) {
                int ar = row0 + mt * 16 + ln; if (ar >= N) ar = N - 1;
                afr[mt] = *(const short8*)(Abf + (size_t)ar * NH + kc * 32 + quad * 8);
            }
        }
#pragma unroll
        for (int nt = 0; nt < 8; ++nt) {
            short8 bfr = *(const short8*)(Wl + ((nt * 4 + kc) * 4 + quad) * 128 + ln * 8);
            acc[0][nt] = __builtin_amdgcn_mfma_f32_16x16x32_bf16(afr[0], bfr, acc[0][nt], 0, 0, 0);
            acc[1][nt] = __builtin_amdgcn_mfma_f32_16x16x32_bf16(afr[1], bfr, acc[1][nt], 0, 0, 0);
        }
    }

#pragma unroll
    for (int mt = 0; mt < 2; ++mt)
#pragma unroll
        for (int r = 0; r < 4; ++r) {
            int row = row0 + mt * 16 + quad * 4 + r;
            if (row < N) {
#pragma unroll
                for (int nt = 0; nt < 8; ++nt) {
                    int col = nt * 16 + ln;
                    float v = acc[mt][nt][r];
                    if (Zf) Zf[(size_t)row * NH + col] = v;
                    if (Zbf) Zbf[(size_t)row * NH + col] = f2bf(v);
                }
            }
        }

    if (bnsum) {
#pragma unroll
        for (int nt = 0; nt < 8; ++nt) {
            float s = 0.f, q = 0.f;
#pragma unroll
            for (int mt = 0; mt < 2; ++mt)
#pragma unroll
                for (int r = 0; r < 4; ++r) {
                    int row = row0 + mt * 16 + quad * 4 + r;
                    if (row < N) { float v = acc[mt][nt][r]; s += v; q += v * v; }
                }
            s += __shfl_xor(s, 16); s += __shfl_xor(s, 32);
            q += __shfl_xor(q, 16); q += __shfl_xor(q, 32);
            if (quad == 0) {
                atomicAdd(&bnL[nt * 16 + ln], s);
                atomicAdd(&bnL[NH + nt * 16 + ln], q);
            }
        }
        __syncthreads();
        if (t < NH) {
            atomicAdd(&bnsum[t], bnL[t]);
            atomicAdd(&bnsumsq[t], bnL[NH + t]);
        }
    }
}

// ---------------- fused: BN finalize + h=relu(zbf*sc+sh)+h + hbf + pool --------------
__global__ __launch_bounds__(256) void update_pool_kernel(
    const unsigned* __restrict__ zbfu, float* __restrict__ h, unsigned* __restrict__ hbfu,
    const float* __restrict__ bnsum, const float* __restrict__ bnsumsq,
    const float* __restrict__ gamma, const float* __restrict__ beta,
    float invN, const int* __restrict__ gstart, float* __restrict__ pooled) {
    int g = blockIdx.x, t = threadIdx.x;
    __shared__ float scL[NH], shL[NH];
    __shared__ float2 red[256];
    if (t < NH) {
        float mu = bnsum[t] * invN;
        float var = fmaf(bnsumsq[t], invN, -mu * mu);
        float sc = gamma[t] * rsqrtf(var + 1e-5f);
        scL[t] = sc;
        shL[t] = beta[t] - mu * sc;
    }
    __syncthreads();
    int s = gstart[g], e = gstart[g + 1];
    int c2 = t & 63, half = t >> 6;
    float2 sc = make_float2(scL[2 * c2], scL[2 * c2 + 1]);
    float2 sh = make_float2(shL[2 * c2], shL[2 * c2 + 1]);
    float2 pacc = make_float2(0.f, 0.f);
    for (int n = s + half; n < e; n += 4) {
        size_t i = (size_t)n * 64 + c2;
        unsigned zu = zbfu[i];
        float2 hv = ((float2*)h)[i];
        float rx = fmaxf(fmaf(bflo(zu), sc.x, sh.x), 0.f) + hv.x;
        float ry = fmaxf(fmaf(bfhi(zu), sc.y, sh.y), 0.f) + hv.y;
        ((float2*)h)[i] = make_float2(rx, ry);
        hbfu[i] = packbf(rx, ry);
        pacc.x += rx; pacc.y += ry;
    }
    red[t] = pacc;
    __syncthreads();
    if (t < 64) {
        float2 a = red[t], b = red[t + 64], c = red[t + 128], d = red[t + 192];
        ((float2*)pooled)[(size_t)g * 64 + c2] =
            make_float2((a.x + b.x) + (c.x + d.x), (a.y + b.y) + (c.y + d.y));
    }
}

// ---------------- pool (layer 0, fp32 h) ----------------
__global__ __launch_bounds__(256) void pool_kernel(
    const float* __restrict__ h, const int* __restrict__ gstart,
    float* __restrict__ pooled, int G) {
    int g = blockIdx.x;
    int t = threadIdx.x;
    int s = gstart[g], e = gstart[g + 1];
    int c = t & 127, half = t >> 7;
    float acc = 0.f;
    for (int n = s + half; n < e; n += 2)
        acc += h[(size_t)n * NH + c];
    __shared__ float red[256];
    red[t] = acc;
    __syncthreads();
    if (t < NH) pooled[(size_t)g * NH + t] = red[t] + red[t + NH];
}

// ---------------- JK head ----------------
__global__ void jk_kernel(const float* __restrict__ pooled, const float* __restrict__ jkW,
                          const float* __restrict__ jkb, float* __restrict__ out, int G) {
    int idx = blockIdx.x * blockDim.x + threadIdx.x;
    if (idx >= G * 10) return;
    int g = idx / 10, c = idx % 10;
    float acc = 0.f;
    for (int l = 0; l < LAYERS + 1; ++l) {
        acc += jkb[l * 10 + c];
        const float* pg = pooled + ((size_t)l * G + g) * NH;
        const float* wl = jkW + (size_t)l * NH * 10 + c;
        float s = 0.f;
#pragma unroll 16
        for (int k = 0; k < NH; ++k) s = fmaf(pg[k], wl[k * 10], s);
        acc += s;
    }
    out[idx] = acc;
}

extern "C" void kernel_launch(void* const* d_in, const int* in_sizes, int n_in,
                              void* d_out, int out_size, void* d_ws, size_t ws_size,
                              hipStream_t stream) {
    const float* h_in      = (const float*)d_in[0];
    const float* edge_attr = (const float*)d_in[1];
    const int*   edge_idx  = (const int*)d_in[2];
    const int*   batch     = (const int*)d_in[5];
    const float* emb_W     = (const float*)d_in[6];
    const float* emb_b     = (const float*)d_in[7];
    const float* conv_W    = (const float*)d_in[8];
    const float* conv_b    = (const float*)d_in[9];
    const float* conv_We   = (const float*)d_in[10];
    const float* conv_be   = (const float*)d_in[11];
    const float* bn_gamma  = (const float*)d_in[12];
    const float* bn_beta   = (const float*)d_in[13];
    const float* jk_W      = (const float*)d_in[14];
    const float* jk_b      = (const float*)d_in[15];
    float* out = (float*)d_out;

    const int N = in_sizes[0] / NH;
    const int E = in_sizes[1] / 16;
    const int G = out_size / 10;
    const int NBKT = (N + BW - 1) / BW;     // <= 1024 assumed

    const int* src = edge_idx;
    const int* dst = edge_idx + E;

    size_t off = 0;
    auto alloc = [&](size_t bytes) -> void* {
        void* p = (char*)d_ws + off;
        off += (bytes + 255) & ~(size_t)255;
        return p;
    };
    float* hbuf = (float*)alloc((size_t)N * NH * 4);
    unsigned short* hbf = (unsigned short*)alloc((size_t)N * NH * 2);
    unsigned short* xbf = (unsigned short*)alloc((size_t)N * NH * 2);
    unsigned short* zbf = (unsigned short*)alloc((size_t)N * NH * 2);
    float* pooled  = (float*)alloc((size_t)(LAYERS + 1) * G * NH * 4);
    float* easum   = (float*)alloc((size_t)N * 16 * 4);
    size_t zero_off = off;
    float* bnsum   = (float*)alloc((size_t)LAYERS * NH * 4);
    float* bnsumsq = (float*)alloc((size_t)LAYERS * NH * 4);
    int* bcnt      = (int*)alloc((size_t)NBKT * 4);
    size_t zero_bytes = off - zero_off;
    int* bktOff    = (int*)alloc((size_t)(NBKT + 1) * 4);
    int* bcur      = (int*)alloc((size_t)NBKT * 4);
    int* gstart    = (int*)alloc((size_t)(G + 1) * 4);
    int* row_start = (int*)alloc((size_t)(N + 1) * 4);
    int2* bkt      = (int2*)alloc((size_t)E * 8);
    int2* pk       = (int2*)alloc((size_t)E * 8);
    (void)ws_size; (void)n_in;

    hipMemsetAsync((char*)d_ws + zero_off, 0, zero_bytes, stream);

    int mEN = (E > N ? E : N);
    bcnt_gstart_kernel<<<(mEN + 255) / 256, 256, 0, stream>>>(dst, bcnt, E, batch, gstart, N, G);
    bscan_kernel<<<1, 1024, 0, stream>>>(bcnt, bktOff, bcur, NBKT);
    bscatter_kernel<<<(E + 255) / 256, 256, 0, stream>>>(src, dst, bcur, bkt, E);
    bfinal_kernel<<<NBKT, 256, 0, stream>>>(bkt, bktOff, row_start, pk, N, E, NBKT);
    easum_kernel<<<(N + 15) / 16, 256, 0, stream>>>(edge_attr, pk, row_start, easum, N);

    dim3 gemm_grid((N + 127) / 128);
    dim3 agg_grid((N + 3) / 4);

    // embedding: fp32 A path; writes hbuf (fp32) + hbf (bf16)
    gemm_mfma_kernel<<<gemm_grid, 256, 0, stream>>>(
        nullptr, h_in, emb_W, emb_b, hbuf, hbf, N, nullptr, nullptr);
    pool_kernel<<<G, 256, 0, stream>>>(hbuf, gstart, pooled, G);

    for (int l = 0; l < LAYERS; ++l) {
        aggregate_kernel<<<agg_grid, 256, 0, stream>>>(
            (const unsigned*)hbf, pk, row_start, easum,
            conv_We + (size_t)l * 16 * NH, conv_be + (size_t)l * NH,
            (unsigned*)xbf, N);
        gemm_mfma_kernel<<<gemm_grid, 256, 0, stream>>>(
            xbf, nullptr, conv_W + (size_t)l * NH * NH, conv_b + (size_t)l * NH,
            nullptr, zbf, N, bnsum + (size_t)l * NH, bnsumsq + (size_t)l * NH);
        update_pool_kernel<<<G, 256, 0, stream>>>(
            (const unsigned*)zbf, hbuf, (unsigned*)hbf,
            bnsum + (size_t)l * NH, bnsumsq + (size_t)l * NH,
            bn_gamma + (size_t)l * NH, bn_beta + (size_t)l * NH,
            1.0f / (float)N, gstart, pooled + (size_t)(l + 1) * G * NH);
    }

    jk_kernel<<<(G * 10 + 255) / 256, 256, 0, stream>>>(pooled, jk_W, jk_b, out, G);
}

// Round 8
// 634.868 us; speedup vs baseline: 1.8423x; 1.8423x over previous
//
#include <hip/hip_runtime.h>

#define NH 128
#define LAYERS 4
#define BW 128          // nodes per CSR bucket (power of 2)
#define CHUNK 4096      // edges per counting-sort chunk

typedef __attribute__((ext_vector_type(8))) short short8;
typedef __attribute__((ext_vector_type(4))) float f32x4;

__device__ __forceinline__ unsigned short f2bf(float f) {
    unsigned u = __float_as_uint(f);
    u += 0x7fffu + ((u >> 16) & 1u);          // round-to-nearest-even
    return (unsigned short)(u >> 16);
}
__device__ __forceinline__ float bflo(unsigned u) { return __uint_as_float(u << 16); }
__device__ __forceinline__ float bfhi(unsigned u) { return __uint_as_float(u & 0xffff0000u); }
__device__ __forceinline__ unsigned packbf(float x, float y) {
    return (unsigned)f2bf(x) | ((unsigned)f2bf(y) << 16);
}

// ---------------- phase A: per-chunk LDS bucket histogram + gstart -------------------
// gH layout bucket-major: gH[bucket * NCH + chunk]. Fully overwritten -> no memset.
__global__ __launch_bounds__(256) void bhist_kernel(const int* __restrict__ dst, int E,
                                                    int* __restrict__ gH, int NBKT, int NCH,
                                                    const int* __restrict__ batch,
                                                    int* __restrict__ gstart, int N, int G) {
    __shared__ int hist[512];
    int b = blockIdx.x, t = threadIdx.x;
    for (int i = t; i < NBKT; i += 256) hist[i] = 0;
    __syncthreads();
    int base = b * CHUNK, end = min(base + CHUNK, E);
    for (int e = base + t; e < end; e += 256)
        atomicAdd(&hist[dst[e] >> 7], 1);
    __syncthreads();
    for (int i = t; i < NBKT; i += 256) gH[i * NCH + b] = hist[i];

    // gstart from sorted batch (grid-stride)
    for (int i = b * 256 + t; i < N; i += gridDim.x * 256) {
        int bb = batch[i];
        int prev = (i == 0) ? -1 : batch[i - 1];
        for (int g = prev + 1; g <= bb; ++g) gstart[g] = i;
        if (i == N - 1)
            for (int g = bb + 1; g <= G; ++g) gstart[g] = N;
    }
}

// ---------------- hierarchical exclusive scan (from R6, proven) ----------------------
__global__ __launch_bounds__(256) void block_sum_kernel(const int* __restrict__ deg,
                                                        int* __restrict__ bsum, int n) {
    __shared__ int red[256];
    int t = threadIdx.x;
    int base = blockIdx.x * 1024;
    int s = 0;
#pragma unroll
    for (int i = 0; i < 4; ++i) {
        int idx = base + i * 256 + t;
        if (idx < n) s += deg[idx];
    }
    red[t] = s;
    __syncthreads();
    for (int off = 128; off > 0; off >>= 1) {
        if (t < off) red[t] += red[t + off];
        __syncthreads();
    }
    if (t == 0) bsum[blockIdx.x] = red[0];
}

__global__ __launch_bounds__(1024) void scan_partials_kernel(int* __restrict__ bsum, int nb,
                                                             int* __restrict__ total_out, int n) {
    __shared__ int part[1024];
    int t = threadIdx.x;
    int v = (t < nb) ? bsum[t] : 0;
    part[t] = v;
    __syncthreads();
    for (int off = 1; off < 1024; off <<= 1) {
        int u = (t >= off) ? part[t - off] : 0;
        __syncthreads();
        part[t] += u;
        __syncthreads();
    }
    if (t < nb) bsum[t] = part[t] - v;
    if (t == 1023) total_out[n] = part[1023];
}

__global__ __launch_bounds__(256) void local_scan_kernel(const int* __restrict__ deg,
                                                         const int* __restrict__ bsum,
                                                         int* __restrict__ outA, int n) {
    __shared__ int part[256];
    int t = threadIdx.x;
    int base = blockIdx.x * 1024 + t * 4;
    int v0 = 0, v1 = 0, v2 = 0, v3 = 0;
    if (base + 3 < n) {
        int4 v = *(const int4*)(deg + base);
        v0 = v.x; v1 = v.y; v2 = v.z; v3 = v.w;
    } else {
        if (base + 0 < n) v0 = deg[base + 0];
        if (base + 1 < n) v1 = deg[base + 1];
        if (base + 2 < n) v2 = deg[base + 2];
        if (base + 3 < n) v3 = deg[base + 3];
    }
    int tsum = v0 + v1 + v2 + v3;
    part[t] = tsum;
    __syncthreads();
    for (int off = 1; off < 256; off <<= 1) {
        int u = (t >= off) ? part[t - off] : 0;
        __syncthreads();
        part[t] += u;
        __syncthreads();
    }
    int run = bsum[blockIdx.x] + part[t] - tsum;
    int r0 = run, r1 = run + v0, r2 = r1 + v1, r3 = r2 + v2;
    if (base + 3 < n) {
        *(int4*)(outA + base) = make_int4(r0, r1, r2, r3);
    } else {
        if (base + 0 < n) outA[base + 0] = r0;
        if (base + 1 < n) outA[base + 1] = r1;
        if (base + 2 < n) outA[base + 2] = r2;
        if (base + 3 < n) outA[base + 3] = r3;
    }
}

// ---------------- phase C: place edges into buckets (LDS cursors, no global atomics) -
__global__ __launch_bounds__(256) void bplace_kernel(const int* __restrict__ src,
                                                     const int* __restrict__ dst, int E,
                                                     const int* __restrict__ gOff,
                                                     int NBKT, int NCH,
                                                     int2* __restrict__ bkt) {
    __shared__ int cur[512];
    int b = blockIdx.x, t = threadIdx.x;
    for (int i = t; i < NBKT; i += 256) cur[i] = gOff[i * NCH + b];
    __syncthreads();
    int base = b * CHUNK, end = min(base + CHUNK, E);
    for (int e = base + t; e < end; e += 256) {
        int d = dst[e];
        int p = atomicAdd(&cur[d >> 7], 1);
        bkt[p] = make_int2(src[e], ((d & (BW - 1)) << 25) | e);   // E < 2^25
    }
}

// ---------------- per-bucket finalize: row_start slice + ordered pk ------------------
__global__ __launch_bounds__(256) void bfinal_kernel(const int2* __restrict__ bkt,
                                                     const int* __restrict__ gOff, int NCH,
                                                     int* __restrict__ row_start,
                                                     int2* __restrict__ pk,
                                                     int N, int E) {
    __shared__ int cnt[BW], par[BW];
    int b = blockIdx.x, t = threadIdx.x;
    int s = gOff[b * NCH];
    int e = (b + 1 < (int)gridDim.x) ? gOff[(b + 1) * NCH] : E;
    if (t < BW) cnt[t] = 0;
    __syncthreads();
    for (int p = s + t; p < e; p += 256)
        atomicAdd(&cnt[(unsigned)bkt[p].y >> 25], 1);
    __syncthreads();
    if (t < BW) par[t] = cnt[t];
    __syncthreads();
    for (int off = 1; off < BW; off <<= 1) {
        int u = (t < BW && t >= off) ? par[t - off] : 0;
        __syncthreads();
        if (t < BW) par[t] += u;
        __syncthreads();
    }
    int node = b * BW + t;
    if (t < BW) {
        int excl = par[t] - cnt[t];
        if (node <= N) row_start[node] = s + excl;
        cnt[t] = s + excl;            // becomes the local cursor
    }
    if (b == 0 && t == 0) row_start[N] = E;
    __syncthreads();
    for (int p = s + t; p < e; p += 256) {
        int2 v = bkt[p];
        int dloc = (unsigned)v.y >> 25;
        int pos = atomicAdd(&cnt[dloc], 1);
        pk[pos] = make_int2(v.x, v.y & 0x1FFFFFF);
    }
}

// ---------------- easum[n][k] = sum over in-edges of edge_attr[e][k] -----------------
__global__ __launch_bounds__(256) void easum_kernel(const float* __restrict__ edge_attr,
                                                    const int2* __restrict__ pk,
                                                    const int* __restrict__ row_start,
                                                    float* __restrict__ easum, int N) {
    int t = threadIdx.x;
    int node = blockIdx.x * 16 + (t >> 4);
    int k = t & 15;
    if (node >= N) return;
    int rs = row_start[node], re = row_start[node + 1];
    float acc = 0.f;
    for (int p = rs; p < re; ++p)
        acc += edge_attr[(size_t)pk[p].y * 16 + k];
    easum[node * 16 + k] = acc;
}

// ---------------- aggregate: xbf = bf16( h_self + sum_in h[src] + easum@We + deg*be )
__global__ __launch_bounds__(256) void aggregate_kernel(
    const unsigned* __restrict__ hbfu, const int2* __restrict__ pk,
    const int* __restrict__ row_start, const float* __restrict__ easum,
    const float* __restrict__ We, const float* __restrict__ be,
    unsigned* __restrict__ xbfu, int N) {
    __shared__ float2 WeL[16 * 64];
    int t = threadIdx.x;
    const float2* Wg2 = (const float2*)We;
    for (int i = t; i < 16 * 64; i += 256) WeL[i] = Wg2[i];
    __syncthreads();

    int wave = t >> 6, lane = t & 63;
    int n = blockIdx.x * 4 + wave;
    if (n >= N) return;
    unsigned uself = hbfu[(size_t)n * 64 + lane];
    float2 acc = make_float2(bflo(uself), bfhi(uself));
    float2 acc2 = make_float2(0.f, 0.f);
    float2 acc3 = make_float2(0.f, 0.f);
    float2 acc4 = make_float2(0.f, 0.f);
    int rs = row_start[n], re = row_start[n + 1];
    float myea = (lane < 16) ? easum[n * 16 + lane] : 0.f;

    for (int base = rs; base < re; base += 64) {
        int cnt = min(64, re - base);
        int myS = (base + lane < re) ? pk[base + lane].x : 0;
        int j = 0;
        for (; j + 15 < cnt; j += 16) {
            int s0 = __shfl(myS, j);      int s1 = __shfl(myS, j + 1);
            int s2 = __shfl(myS, j + 2);  int s3 = __shfl(myS, j + 3);
            int s4 = __shfl(myS, j + 4);  int s5 = __shfl(myS, j + 5);
            int s6 = __shfl(myS, j + 6);  int s7 = __shfl(myS, j + 7);
            int s8 = __shfl(myS, j + 8);  int s9 = __shfl(myS, j + 9);
            int sa = __shfl(myS, j + 10); int sb = __shfl(myS, j + 11);
            int sc = __shfl(myS, j + 12); int sd = __shfl(myS, j + 13);
            int se = __shfl(myS, j + 14); int sf = __shfl(myS, j + 15);
            unsigned u0 = hbfu[(size_t)s0 * 64 + lane];
            unsigned u1 = hbfu[(size_t)s1 * 64 + lane];
            unsigned u2 = hbfu[(size_t)s2 * 64 + lane];
            unsigned u3 = hbfu[(size_t)s3 * 64 + lane];
            unsigned u4 = hbfu[(size_t)s4 * 64 + lane];
            unsigned u5 = hbfu[(size_t)s5 * 64 + lane];
            unsigned u6 = hbfu[(size_t)s6 * 64 + lane];
            unsigned u7 = hbfu[(size_t)s7 * 64 + lane];
            unsigned u8 = hbfu[(size_t)s8 * 64 + lane];
            unsigned u9 = hbfu[(size_t)s9 * 64 + lane];
            unsigned ua = hbfu[(size_t)sa * 64 + lane];
            unsigned ub = hbfu[(size_t)sb * 64 + lane];
            unsigned uc = hbfu[(size_t)sc * 64 + lane];
            unsigned ud = hbfu[(size_t)sd * 64 + lane];
            unsigned ue = hbfu[(size_t)se * 64 + lane];
            unsigned uf = hbfu[(size_t)sf * 64 + lane];
            acc.x  += bflo(u0) + bflo(u1) + bflo(u2) + bflo(u3);
            acc.y  += bfhi(u0) + bfhi(u1) + bfhi(u2) + bfhi(u3);
            acc2.x += bflo(u4) + bflo(u5) + bflo(u6) + bflo(u7);
            acc2.y += bfhi(u4) + bfhi(u5) + bfhi(u6) + bfhi(u7);
            acc3.x += bflo(u8) + bflo(u9) + bflo(ua) + bflo(ub);
            acc3.y += bfhi(u8) + bfhi(u9) + bfhi(ua) + bfhi(ub);
            acc4.x += bflo(uc) + bflo(ud) + bflo(ue) + bflo(uf);
            acc4.y += bfhi(uc) + bfhi(ud) + bfhi(ue) + bfhi(uf);
        }
        for (; j + 3 < cnt; j += 4) {
            int s0 = __shfl(myS, j);
            int s1 = __shfl(myS, j + 1);
            int s2 = __shfl(myS, j + 2);
            int s3 = __shfl(myS, j + 3);
            unsigned u0 = hbfu[(size_t)s0 * 64 + lane];
            unsigned u1 = hbfu[(size_t)s1 * 64 + lane];
            unsigned u2 = hbfu[(size_t)s2 * 64 + lane];
            unsigned u3 = hbfu[(size_t)s3 * 64 + lane];
            acc.x += bflo(u0) + bflo(u1) + bflo(u2) + bflo(u3);
            acc.y += bfhi(u0) + bfhi(u1) + bfhi(u2) + bfhi(u3);
        }
        for (; j < cnt; ++j) {
            int s = __shfl(myS, j);
            unsigned u = hbfu[(size_t)s * 64 + lane];
            acc.x += bflo(u);
            acc.y += bfhi(u);
        }
    }
    acc.x += (acc2.x + acc3.x) + acc4.x;
    acc.y += (acc2.y + acc3.y) + acc4.y;

    float degf = (float)(re - rs);
    float2 be2 = ((const float2*)be)[lane];
#pragma unroll
    for (int k = 0; k < 16; ++k) {
        float e = __shfl(myea, k);
        float2 w = WeL[k * 64 + lane];
        acc.x = fmaf(e, w.x, acc.x);
        acc.y = fmaf(e, w.y, acc.y);
    }
    acc.x += degf * be2.x;
    acc.y += degf * be2.y;
    xbfu[(size_t)n * 64 + lane] = packbf(acc.x, acc.y);
}

// ---------------- MFMA GEMM: Z = A @ W + b ------------------------------------------
__global__ __launch_bounds__(256) void gemm_mfma_kernel(
    const unsigned short* __restrict__ Abf, const float* __restrict__ Af32,
    const float* __restrict__ W, const float* __restrict__ bias,
    float* __restrict__ Zf, unsigned short* __restrict__ Zbf,
    int N, float* __restrict__ bnsum, float* __restrict__ bnsumsq) {
    __shared__ unsigned short Wl[128 * 128];   // 32KB, swizzled [nt][kc][quad][ln*8+j]
    __shared__ float bnL[2 * NH];
    int t = threadIdx.x;
    for (int i = t; i < 128 * 64; i += 256) {
        float2 w2 = ((const float2*)W)[i];
        int k = i >> 6, n = (i & 63) * 2;
        int kc = k >> 5, quad = (k >> 3) & 3, j = k & 7;
        int base = (((n >> 4) * 4 + kc) * 4 + quad) * 128 + j;
        Wl[base + ((n & 15) << 3)] = f2bf(w2.x);
        Wl[base + (((n + 1) & 15) << 3)] = f2bf(w2.y);
    }
    if (t < 2 * NH) bnL[t] = 0.f;
    __syncthreads();

    int wave = t >> 6, lane = t & 63;
    int quad = lane >> 4, ln = lane & 15;
    int row0 = blockIdx.x * 128 + wave * 32;

    f32x4 acc[2][8];
#pragma unroll
    for (int nt = 0; nt < 8; ++nt) {
        float bv = bias[nt * 16 + ln];
        acc[0][nt] = (f32x4){bv, bv, bv, bv};
        acc[1][nt] = (f32x4){bv, bv, bv, bv};
    }

    for (int kc = 0; kc < 4; ++kc) {
        short8 afr[2];
        if (Af32) {
#pragma unroll
            for (int mt = 0; mt < 2; ++mt) {
                int ar = row0 + mt * 16 + ln; if (ar >= N) ar = N - 1;
                const float4* ap = (const float4*)(Af32 + (size_t)ar * NH + kc * 32 + quad * 8);
                float4 a0 = ap[0], a1 = ap[1];
                short8 v;
                v[0] = (short)f2bf(a0.x); v[1] = (short)f2bf(a0.y);
                v[2] = (short)f2bf(a0.z); v[3] = (short)f2bf(a0.w);
                v[4] = (short)f2bf(a1.x); v[5] = (short)f2bf(a1.y);
                v[6] = (short)f2bf(a1.z); v[7] = (short)f2bf(a1.w);
                afr[mt] = v;
            }
        } else {
#pragma unroll
            for (int mt = 0; mt < 2; ++mt) {
                int ar = row0 + mt * 16 + ln; if (ar >= N) ar = N - 1;
                afr[mt] = *(const short8*)(Abf + (size_t)ar * NH + kc * 32 + quad * 8);
            }
        }
#pragma unroll
        for (int nt = 0; nt < 8; ++nt) {
            short8 bfr = *(const short8*)(Wl + ((nt * 4 + kc) * 4 + quad) * 128 + ln * 8);
            acc[0][nt] = __builtin_amdgcn_mfma_f32_16x16x32_bf16(afr[0], bfr, acc[0][nt], 0, 0, 0);
            acc[1][nt] = __builtin_amdgcn_mfma_f32_16x16x32_bf16(afr[1], bfr, acc[1][nt], 0, 0, 0);
        }
    }

#pragma unroll
    for (int mt = 0; mt < 2; ++mt)
#pragma unroll
        for (int r = 0; r < 4; ++r) {
            int row = row0 + mt * 16 + quad * 4 + r;
            if (row < N) {
#pragma unroll
                for (int nt = 0; nt < 8; ++nt) {
                    int col = nt * 16 + ln;
                    float v = acc[mt][nt][r];
                    if (Zf) Zf[(size_t)row * NH + col] = v;
                    if (Zbf) Zbf[(size_t)row * NH + col] = f2bf(v);
                }
            }
        }

    if (bnsum) {
#pragma unroll
        for (int nt = 0; nt < 8; ++nt) {
            float s = 0.f, q = 0.f;
#pragma unroll
            for (int mt = 0; mt < 2; ++mt)
#pragma unroll
                for (int r = 0; r < 4; ++r) {
                    int row = row0 + mt * 16 + quad * 4 + r;
                    if (row < N) { float v = acc[mt][nt][r]; s += v; q += v * v; }
                }
            s += __shfl_xor(s, 16); s += __shfl_xor(s, 32);
            q += __shfl_xor(q, 16); q += __shfl_xor(q, 32);
            if (quad == 0) {
                atomicAdd(&bnL[nt * 16 + ln], s);
                atomicAdd(&bnL[NH + nt * 16 + ln], q);
            }
        }
        __syncthreads();
        if (t < NH) {
            atomicAdd(&bnsum[t], bnL[t]);
            atomicAdd(&bnsumsq[t], bnL[NH + t]);
        }
    }
}

// ---------------- fused: BN finalize + h=relu(zbf*sc+sh)+h + hbf + pool --------------
__global__ __launch_bounds__(256) void update_pool_kernel(
    const unsigned* __restrict__ zbfu, float* __restrict__ h, unsigned* __restrict__ hbfu,
    const float* __restrict__ bnsum, const float* __restrict__ bnsumsq,
    const float* __restrict__ gamma, const float* __restrict__ beta,
    float invN, const int* __restrict__ gstart, float* __restrict__ pooled) {
    int g = blockIdx.x, t = threadIdx.x;
    __shared__ float scL[NH], shL[NH];
    __shared__ float2 red[256];
    if (t < NH) {
        float mu = bnsum[t] * invN;
        float var = fmaf(bnsumsq[t], invN, -mu * mu);
        float sc = gamma[t] * rsqrtf(var + 1e-5f);
        scL[t] = sc;
        shL[t] = beta[t] - mu * sc;
    }
    __syncthreads();
    int s = gstart[g], e = gstart[g + 1];
    int c2 = t & 63, half = t >> 6;
    float2 sc = make_float2(scL[2 * c2], scL[2 * c2 + 1]);
    float2 sh = make_float2(shL[2 * c2], shL[2 * c2 + 1]);
    float2 pacc = make_float2(0.f, 0.f);
    for (int n = s + half; n < e; n += 4) {
        size_t i = (size_t)n * 64 + c2;
        unsigned zu = zbfu[i];
        float2 hv = ((float2*)h)[i];
        float rx = fmaxf(fmaf(bflo(zu), sc.x, sh.x), 0.f) + hv.x;
        float ry = fmaxf(fmaf(bfhi(zu), sc.y, sh.y), 0.f) + hv.y;
        ((float2*)h)[i] = make_float2(rx, ry);
        hbfu[i] = packbf(rx, ry);
        pacc.x += rx; pacc.y += ry;
    }
    red[t] = pacc;
    __syncthreads();
    if (t < 64) {
        float2 a = red[t], b = red[t + 64], c = red[t + 128], d = red[t + 192];
        ((float2*)pooled)[(size_t)g * 64 + c2] =
            make_float2((a.x + b.x) + (c.x + d.x), (a.y + b.y) + (c.y + d.y));
    }
}

// ---------------- pool (layer 0, fp32 h) ----------------
__global__ __launch_bounds__(256) void pool_kernel(
    const float* __restrict__ h, const int* __restrict__ gstart,
    float* __restrict__ pooled, int G) {
    int g = blockIdx.x;
    int t = threadIdx.x;
    int s = gstart[g], e = gstart[g + 1];
    int c = t & 127, half = t >> 7;
    float acc = 0.f;
    for (int n = s + half; n < e; n += 2)
        acc += h[(size_t)n * NH + c];
    __shared__ float red[256];
    red[t] = acc;
    __syncthreads();
    if (t < NH) pooled[(size_t)g * NH + t] = red[t] + red[t + NH];
}

// ---------------- JK head ----------------
__global__ void jk_kernel(const float* __restrict__ pooled, const float* __restrict__ jkW,
                          const float* __restrict__ jkb, float* __restrict__ out, int G) {
    int idx = blockIdx.x * blockDim.x + threadIdx.x;
    if (idx >= G * 10) return;
    int g = idx / 10, c = idx % 10;
    float acc = 0.f;
    for (int l = 0; l < LAYERS + 1; ++l) {
        acc += jkb[l * 10 + c];
        const float* pg = pooled + ((size_t)l * G + g) * NH;
        const float* wl = jkW + (size_t)l * NH * 10 + c;
        float s = 0.f;
#pragma unroll 16
        for (int k = 0; k < NH; ++k) s = fmaf(pg[k], wl[k * 10], s);
        acc += s;
    }
    out[idx] = acc;
}

extern "C" void kernel_launch(void* const* d_in, const int* in_sizes, int n_in,
                              void* d_out, int out_size, void* d_ws, size_t ws_size,
                              hipStream_t stream) {
    const float* h_in      = (const float*)d_in[0];
    const float* edge_attr = (const float*)d_in[1];
    const int*   edge_idx  = (const int*)d_in[2];
    const int*   batch     = (const int*)d_in[5];
    const float* emb_W     = (const float*)d_in[6];
    const float* emb_b     = (const float*)d_in[7];
    const float* conv_W    = (const float*)d_in[8];
    const float* conv_b    = (const float*)d_in[9];
    const float* conv_We   = (const float*)d_in[10];
    const float* conv_be   = (const float*)d_in[11];
    const float* bn_gamma  = (const float*)d_in[12];
    const float* bn_beta   = (const float*)d_in[13];
    const float* jk_W      = (const float*)d_in[14];
    const float* jk_b      = (const float*)d_in[15];
    float* out = (float*)d_out;

    const int N = in_sizes[0] / NH;
    const int E = in_sizes[1] / 16;
    const int G = out_size / 10;
    const int NBKT = (N + BW - 1) / BW;          // 391 (<= 512)
    const int NCH  = (E + CHUNK - 1) / CHUNK;    // 196
    const int NTOT = NBKT * NCH;                 // ~77k
    const int NBW  = (NTOT + 1023) / 1024;       // ~75 (<= 1024)

    const int* src = edge_idx;
    const int* dst = edge_idx + E;

    size_t off = 0;
    auto alloc = [&](size_t bytes) -> void* {
        void* p = (char*)d_ws + off;
        off += (bytes + 255) & ~(size_t)255;
        return p;
    };
    float* hbuf = (float*)alloc((size_t)N * NH * 4);
    unsigned short* hbf = (unsigned short*)alloc((size_t)N * NH * 2);
    unsigned short* xbf = (unsigned short*)alloc((size_t)N * NH * 2);
    unsigned short* zbf = (unsigned short*)alloc((size_t)N * NH * 2);
    float* pooled  = (float*)alloc((size_t)(LAYERS + 1) * G * NH * 4);
    float* easum   = (float*)alloc((size_t)N * 16 * 4);
    size_t zero_off = off;
    float* bnsum   = (float*)alloc((size_t)LAYERS * NH * 4);
    float* bnsumsq = (float*)alloc((size_t)LAYERS * NH * 4);
    size_t zero_bytes = off - zero_off;
    int* gH        = (int*)alloc((size_t)(NTOT + 1) * 4);   // scanned in place -> gOff
    int* bsumW     = (int*)alloc((size_t)NBW * 4);
    int* gstart    = (int*)alloc((size_t)(G + 1) * 4);
    int* row_start = (int*)alloc((size_t)(N + 1) * 4);
    int2* bkt      = (int2*)alloc((size_t)E * 8);
    int2* pk       = (int2*)alloc((size_t)E * 8);
    (void)ws_size; (void)n_in;

    hipMemsetAsync((char*)d_ws + zero_off, 0, zero_bytes, stream);

    // CSR build: block-aggregated counting sort (no global atomics)
    bhist_kernel<<<NCH, 256, 0, stream>>>(dst, E, gH, NBKT, NCH, batch, gstart, N, G);
    block_sum_kernel<<<NBW, 256, 0, stream>>>(gH, bsumW, NTOT);
    scan_partials_kernel<<<1, 1024, 0, stream>>>(bsumW, NBW, gH, NTOT);
    local_scan_kernel<<<NBW, 256, 0, stream>>>(gH, bsumW, gH, NTOT);   // in-place exclusive scan
    bplace_kernel<<<NCH, 256, 0, stream>>>(src, dst, E, gH, NBKT, NCH, bkt);
    bfinal_kernel<<<NBKT, 256, 0, stream>>>(bkt, gH, NCH, row_start, pk, N, E);
    easum_kernel<<<(N + 15) / 16, 256, 0, stream>>>(edge_attr, pk, row_start, easum, N);

    dim3 gemm_grid((N + 127) / 128);
    dim3 agg_grid((N + 3) / 4);

    // embedding: fp32 A path; writes hbuf (fp32) + hbf (bf16)
    gemm_mfma_kernel<<<gemm_grid, 256, 0, stream>>>(
        nullptr, h_in, emb_W, emb_b, hbuf, hbf, N, nullptr, nullptr);
    pool_kernel<<<G, 256, 0, stream>>>(hbuf, gstart, pooled, G);

    for (int l = 0; l < LAYERS; ++l) {
        aggregate_kernel<<<agg_grid, 256, 0, stream>>>(
            (const unsigned*)hbf, pk, row_start, easum,
            conv_We + (size_t)l * 16 * NH, conv_be + (size_t)l * NH,
            (unsigned*)xbf, N);
        gemm_mfma_kernel<<<gemm_grid, 256, 0, stream>>>(
            xbf, nullptr, conv_W + (size_t)l * NH * NH, conv_b + (size_t)l * NH,
            nullptr, zbf, N, bnsum + (size_t)l * NH, bnsumsq + (size_t)l * NH);
        update_pool_kernel<<<G, 256, 0, stream>>>(
            (const unsigned*)zbf, hbuf, (unsigned*)hbf,
            bnsum + (size_t)l * NH, bnsumsq + (size_t)l * NH,
            bn_gamma + (size_t)l * NH, bn_beta + (size_t)l * NH,
            1.0f / (float)N, gstart, pooled + (size_t)(l + 1) * G * NH);
    }

    jk_kernel<<<(G * 10 + 255) / 256, 256, 0, stream>>>(pooled, jk_W, jk_b, out, G);
}

// Round 9
// 549.054 us; speedup vs baseline: 2.1303x; 1.1563x over previous
//
#include <hip/hip_runtime.h>

#define NH 128
#define LAYERS 4
#define BW 128          // nodes per CSR bucket (power of 2)
#define CHUNK 4096      // edges per counting-sort chunk

typedef __attribute__((ext_vector_type(8))) short short8;
typedef __attribute__((ext_vector_type(4))) float f32x4;

__device__ __forceinline__ unsigned short f2bf(float f) {
    unsigned u = __float_as_uint(f);
    u += 0x7fffu + ((u >> 16) & 1u);          // round-to-nearest-even
    return (unsigned short)(u >> 16);
}
__device__ __forceinline__ float bflo(unsigned u) { return __uint_as_float(u << 16); }
__device__ __forceinline__ float bfhi(unsigned u) { return __uint_as_float(u & 0xffff0000u); }
__device__ __forceinline__ unsigned packbf(float x, float y) {
    return (unsigned)f2bf(x) | ((unsigned)f2bf(y) << 16);
}

// ---------------- pre-swizzle 5 weight matrices (emb + 4 conv) to MFMA bf16 layout ---
// dst layout per matrix: Wsw[(((n>>4)*4 + kc)*4 + quad)*128 + (n&15)*8 + j],  k=kc*32+quad*8+j
__global__ void wswz_kernel(const float* __restrict__ emb_W, const float* __restrict__ conv_W,
                            unsigned short* __restrict__ Wsw) {
    int idx = blockIdx.x * 256 + threadIdx.x;   // over 5*8192 float2
    if (idx >= 5 * 8192) return;
    int m = idx >> 13, i = idx & 8191;
    const float* W = (m == 0) ? emb_W : conv_W + (size_t)(m - 1) * 16384;
    float2 w2 = ((const float2*)W)[i];
    int k = i >> 6, n = (i & 63) * 2;
    int kc = k >> 5, quad = (k >> 3) & 3, j = k & 7;
    int base = m * 16384 + (((n >> 4) * 4 + kc) * 4 + quad) * 128 + j;
    Wsw[base + ((n & 15) << 3)] = f2bf(w2.x);
    Wsw[base + (((n + 1) & 15) << 3)] = f2bf(w2.y);
}

// ---------------- phase A: per-chunk LDS bucket histogram + gstart -------------------
__global__ __launch_bounds__(256) void bhist_kernel(const int* __restrict__ dst, int E,
                                                    int* __restrict__ gH, int NBKT, int NCH,
                                                    const int* __restrict__ batch,
                                                    int* __restrict__ gstart, int N, int G) {
    __shared__ int hist[512];
    int b = blockIdx.x, t = threadIdx.x;
    for (int i = t; i < NBKT; i += 256) hist[i] = 0;
    __syncthreads();
    int base = b * CHUNK, end = min(base + CHUNK, E);
    for (int e = base + t; e < end; e += 256)
        atomicAdd(&hist[dst[e] >> 7], 1);
    __syncthreads();
    for (int i = t; i < NBKT; i += 256) gH[i * NCH + b] = hist[i];

    for (int i = b * 256 + t; i < N; i += gridDim.x * 256) {
        int bb = batch[i];
        int prev = (i == 0) ? -1 : batch[i - 1];
        for (int g = prev + 1; g <= bb; ++g) gstart[g] = i;
        if (i == N - 1)
            for (int g = bb + 1; g <= G; ++g) gstart[g] = N;
    }
}

// ---------------- hierarchical exclusive scan ----------------------------------------
__global__ __launch_bounds__(256) void block_sum_kernel(const int* __restrict__ deg,
                                                        int* __restrict__ bsum, int n) {
    __shared__ int red[256];
    int t = threadIdx.x;
    int base = blockIdx.x * 1024;
    int s = 0;
#pragma unroll
    for (int i = 0; i < 4; ++i) {
        int idx = base + i * 256 + t;
        if (idx < n) s += deg[idx];
    }
    red[t] = s;
    __syncthreads();
    for (int off = 128; off > 0; off >>= 1) {
        if (t < off) red[t] += red[t + off];
        __syncthreads();
    }
    if (t == 0) bsum[blockIdx.x] = red[0];
}

__global__ __launch_bounds__(1024) void scan_partials_kernel(int* __restrict__ bsum, int nb,
                                                             int* __restrict__ total_out, int n) {
    __shared__ int part[1024];
    int t = threadIdx.x;
    int v = (t < nb) ? bsum[t] : 0;
    part[t] = v;
    __syncthreads();
    for (int off = 1; off < 1024; off <<= 1) {
        int u = (t >= off) ? part[t - off] : 0;
        __syncthreads();
        part[t] += u;
        __syncthreads();
    }
    if (t < nb) bsum[t] = part[t] - v;
    if (t == 1023) total_out[n] = part[1023];
}

__global__ __launch_bounds__(256) void local_scan_kernel(const int* __restrict__ deg,
                                                         const int* __restrict__ bsum,
                                                         int* __restrict__ outA, int n) {
    __shared__ int part[256];
    int t = threadIdx.x;
    int base = blockIdx.x * 1024 + t * 4;
    int v0 = 0, v1 = 0, v2 = 0, v3 = 0;
    if (base + 3 < n) {
        int4 v = *(const int4*)(deg + base);
        v0 = v.x; v1 = v.y; v2 = v.z; v3 = v.w;
    } else {
        if (base + 0 < n) v0 = deg[base + 0];
        if (base + 1 < n) v1 = deg[base + 1];
        if (base + 2 < n) v2 = deg[base + 2];
        if (base + 3 < n) v3 = deg[base + 3];
    }
    int tsum = v0 + v1 + v2 + v3;
    part[t] = tsum;
    __syncthreads();
    for (int off = 1; off < 256; off <<= 1) {
        int u = (t >= off) ? part[t - off] : 0;
        __syncthreads();
        part[t] += u;
        __syncthreads();
    }
    int run = bsum[blockIdx.x] + part[t] - tsum;
    int r0 = run, r1 = run + v0, r2 = r1 + v1, r3 = r2 + v2;
    if (base + 3 < n) {
        *(int4*)(outA + base) = make_int4(r0, r1, r2, r3);
    } else {
        if (base + 0 < n) outA[base + 0] = r0;
        if (base + 1 < n) outA[base + 1] = r1;
        if (base + 2 < n) outA[base + 2] = r2;
        if (base + 3 < n) outA[base + 3] = r3;
    }
}

// ---------------- phase C: place edges into buckets (LDS cursors) --------------------
__global__ __launch_bounds__(256) void bplace_kernel(const int* __restrict__ src,
                                                     const int* __restrict__ dst, int E,
                                                     const int* __restrict__ gOff,
                                                     int NBKT, int NCH,
                                                     int2* __restrict__ bkt) {
    __shared__ int cur[512];
    int b = blockIdx.x, t = threadIdx.x;
    for (int i = t; i < NBKT; i += 256) cur[i] = gOff[i * NCH + b];
    __syncthreads();
    int base = b * CHUNK, end = min(base + CHUNK, E);
    for (int e = base + t; e < end; e += 256) {
        int d = dst[e];
        int p = atomicAdd(&cur[d >> 7], 1);
        bkt[p] = make_int2(src[e], ((d & (BW - 1)) << 25) | e);   // E < 2^25
    }
}

// ---------------- per-bucket finalize: row_start slice + ordered pk ------------------
__global__ __launch_bounds__(256) void bfinal_kernel(const int2* __restrict__ bkt,
                                                     const int* __restrict__ gOff, int NCH,
                                                     int* __restrict__ row_start,
                                                     int2* __restrict__ pk,
                                                     int N, int E) {
    __shared__ int cnt[BW], par[BW];
    int b = blockIdx.x, t = threadIdx.x;
    int s = gOff[b * NCH];
    int e = (b + 1 < (int)gridDim.x) ? gOff[(b + 1) * NCH] : E;
    if (t < BW) cnt[t] = 0;
    __syncthreads();
    for (int p = s + t; p < e; p += 256)
        atomicAdd(&cnt[(unsigned)bkt[p].y >> 25], 1);
    __syncthreads();
    if (t < BW) par[t] = cnt[t];
    __syncthreads();
    for (int off = 1; off < BW; off <<= 1) {
        int u = (t < BW && t >= off) ? par[t - off] : 0;
        __syncthreads();
        if (t < BW) par[t] += u;
        __syncthreads();
    }
    int node = b * BW + t;
    if (t < BW) {
        int excl = par[t] - cnt[t];
        if (node <= N) row_start[node] = s + excl;
        cnt[t] = s + excl;
    }
    if (b == 0 && t == 0) row_start[N] = E;
    __syncthreads();
    for (int p = s + t; p < e; p += 256) {
        int2 v = bkt[p];
        int dloc = (unsigned)v.y >> 25;
        int pos = atomicAdd(&cnt[dloc], 1);
        pk[pos] = make_int2(v.x, v.y & 0x1FFFFFF);
    }
}

// ---------------- easum ----------------
__global__ __launch_bounds__(256) void easum_kernel(const float* __restrict__ edge_attr,
                                                    const int2* __restrict__ pk,
                                                    const int* __restrict__ row_start,
                                                    float* __restrict__ easum, int N) {
    int t = threadIdx.x;
    int node = blockIdx.x * 16 + (t >> 4);
    int k = t & 15;
    if (node >= N) return;
    int rs = row_start[node], re = row_start[node + 1];
    float acc = 0.f;
    for (int p = rs; p < re; ++p)
        acc += edge_attr[(size_t)pk[p].y * 16 + k];
    easum[node * 16 + k] = acc;
}

// ---------------- aggregate: xbf = bf16( h_self + sum_in h[src] + easum@We + deg*be )
__global__ __launch_bounds__(256) void aggregate_kernel(
    const unsigned* __restrict__ hbfu, const int2* __restrict__ pk,
    const int* __restrict__ row_start, const float* __restrict__ easum,
    const float* __restrict__ We, const float* __restrict__ be,
    unsigned* __restrict__ xbfu, int N) {
    __shared__ float2 WeL[16 * 64];
    int t = threadIdx.x;
    const float2* Wg2 = (const float2*)We;
    for (int i = t; i < 16 * 64; i += 256) WeL[i] = Wg2[i];
    __syncthreads();

    int wave = t >> 6, lane = t & 63;
    int n = blockIdx.x * 4 + wave;
    if (n >= N) return;
    unsigned uself = hbfu[(size_t)n * 64 + lane];
    float2 acc = make_float2(bflo(uself), bfhi(uself));
    float2 acc2 = make_float2(0.f, 0.f);
    float2 acc3 = make_float2(0.f, 0.f);
    float2 acc4 = make_float2(0.f, 0.f);
    int rs = row_start[n], re = row_start[n + 1];
    float myea = (lane < 16) ? easum[n * 16 + lane] : 0.f;

    for (int base = rs; base < re; base += 64) {
        int cnt = min(64, re - base);
        int myS = (base + lane < re) ? pk[base + lane].x : 0;
        int j = 0;
        for (; j + 15 < cnt; j += 16) {
            int s0 = __shfl(myS, j);      int s1 = __shfl(myS, j + 1);
            int s2 = __shfl(myS, j + 2);  int s3 = __shfl(myS, j + 3);
            int s4 = __shfl(myS, j + 4);  int s5 = __shfl(myS, j + 5);
            int s6 = __shfl(myS, j + 6);  int s7 = __shfl(myS, j + 7);
            int s8 = __shfl(myS, j + 8);  int s9 = __shfl(myS, j + 9);
            int sa = __shfl(myS, j + 10); int sb = __shfl(myS, j + 11);
            int sc = __shfl(myS, j + 12); int sd = __shfl(myS, j + 13);
            int se = __shfl(myS, j + 14); int sf = __shfl(myS, j + 15);
            unsigned u0 = hbfu[(size_t)s0 * 64 + lane];
            unsigned u1 = hbfu[(size_t)s1 * 64 + lane];
            unsigned u2 = hbfu[(size_t)s2 * 64 + lane];
            unsigned u3 = hbfu[(size_t)s3 * 64 + lane];
            unsigned u4 = hbfu[(size_t)s4 * 64 + lane];
            unsigned u5 = hbfu[(size_t)s5 * 64 + lane];
            unsigned u6 = hbfu[(size_t)s6 * 64 + lane];
            unsigned u7 = hbfu[(size_t)s7 * 64 + lane];
            unsigned u8 = hbfu[(size_t)s8 * 64 + lane];
            unsigned u9 = hbfu[(size_t)s9 * 64 + lane];
            unsigned ua = hbfu[(size_t)sa * 64 + lane];
            unsigned ub = hbfu[(size_t)sb * 64 + lane];
            unsigned uc = hbfu[(size_t)sc * 64 + lane];
            unsigned ud = hbfu[(size_t)sd * 64 + lane];
            unsigned ue = hbfu[(size_t)se * 64 + lane];
            unsigned uf = hbfu[(size_t)sf * 64 + lane];
            acc.x  += bflo(u0) + bflo(u1) + bflo(u2) + bflo(u3);
            acc.y  += bfhi(u0) + bfhi(u1) + bfhi(u2) + bfhi(u3);
            acc2.x += bflo(u4) + bflo(u5) + bflo(u6) + bflo(u7);
            acc2.y += bfhi(u4) + bfhi(u5) + bfhi(u6) + bfhi(u7);
            acc3.x += bflo(u8) + bflo(u9) + bflo(ua) + bflo(ub);
            acc3.y += bfhi(u8) + bfhi(u9) + bfhi(ua) + bfhi(ub);
            acc4.x += bflo(uc) + bflo(ud) + bflo(ue) + bflo(uf);
            acc4.y += bfhi(uc) + bfhi(ud) + bfhi(ue) + bfhi(uf);
        }
        for (; j + 3 < cnt; j += 4) {
            int s0 = __shfl(myS, j);
            int s1 = __shfl(myS, j + 1);
            int s2 = __shfl(myS, j + 2);
            int s3 = __shfl(myS, j + 3);
            unsigned u0 = hbfu[(size_t)s0 * 64 + lane];
            unsigned u1 = hbfu[(size_t)s1 * 64 + lane];
            unsigned u2 = hbfu[(size_t)s2 * 64 + lane];
            unsigned u3 = hbfu[(size_t)s3 * 64 + lane];
            acc.x += bflo(u0) + bflo(u1) + bflo(u2) + bflo(u3);
            acc.y += bfhi(u0) + bfhi(u1) + bfhi(u2) + bfhi(u3);
        }
        for (; j < cnt; ++j) {
            int s = __shfl(myS, j);
            unsigned u = hbfu[(size_t)s * 64 + lane];
            acc.x += bflo(u);
            acc.y += bfhi(u);
        }
    }
    acc.x += (acc2.x + acc3.x) + acc4.x;
    acc.y += (acc2.y + acc3.y) + acc4.y;

    float degf = (float)(re - rs);
    float2 be2 = ((const float2*)be)[lane];
#pragma unroll
    for (int k = 0; k < 16; ++k) {
        float e = __shfl(myea, k);
        float2 w = WeL[k * 64 + lane];
        acc.x = fmaf(e, w.x, acc.x);
        acc.y = fmaf(e, w.y, acc.y);
    }
    acc.x += degf * be2.x;
    acc.y += degf * be2.y;
    xbfu[(size_t)n * 64 + lane] = packbf(acc.x, acc.y);
}

// ---------------- MFMA GEMM: Zbf = bf16(A @ W + b), W pre-swizzled bf16 --------------
__global__ __launch_bounds__(256) void gemm_mfma_kernel(
    const unsigned short* __restrict__ Abf, const float* __restrict__ Af32,
    const unsigned short* __restrict__ Wsw, const float* __restrict__ bias,
    unsigned short* __restrict__ Zbf,
    int N, float* __restrict__ bnsum, float* __restrict__ bnsumsq) {
    __shared__ unsigned short Wl[128 * 128];   // 32KB pre-swizzled
    __shared__ float bnL[2 * NH];
    int t = threadIdx.x;
    {
        const float4* Wg = (const float4*)Wsw;
        float4* Wl4 = (float4*)Wl;
        for (int i = t; i < 2048; i += 256) Wl4[i] = Wg[i];
    }
    if (t < 2 * NH) bnL[t] = 0.f;
    __syncthreads();

    int wave = t >> 6, lane = t & 63;
    int quad = lane >> 4, ln = lane & 15;
    int row0 = blockIdx.x * 128 + wave * 32;

    f32x4 acc[2][8];
#pragma unroll
    for (int nt = 0; nt < 8; ++nt) {
        float bv = bias[nt * 16 + ln];
        acc[0][nt] = (f32x4){bv, bv, bv, bv};
        acc[1][nt] = (f32x4){bv, bv, bv, bv};
    }

    for (int kc = 0; kc < 4; ++kc) {
        short8 afr[2];
        if (Af32) {
#pragma unroll
            for (int mt = 0; mt < 2; ++mt) {
                int ar = row0 + mt * 16 + ln; if (ar >= N) ar = N - 1;
                const float4* ap = (const float4*)(Af32 + (size_t)ar * NH + kc * 32 + quad * 8);
                float4 a0 = ap[0], a1 = ap[1];
                short8 v;
                v[0] = (short)f2bf(a0.x); v[1] = (short)f2bf(a0.y);
                v[2] = (short)f2bf(a0.z); v[3] = (short)f2bf(a0.w);
                v[4] = (short)f2bf(a1.x); v[5] = (short)f2bf(a1.y);
                v[6] = (short)f2bf(a1.z); v[7] = (short)f2bf(a1.w);
                afr[mt] = v;
            }
        } else {
#pragma unroll
            for (int mt = 0; mt < 2; ++mt) {
                int ar = row0 + mt * 16 + ln; if (ar >= N) ar = N - 1;
                afr[mt] = *(const short8*)(Abf + (size_t)ar * NH + kc * 32 + quad * 8);
            }
        }
#pragma unroll
        for (int nt = 0; nt < 8; ++nt) {
            short8 bfr = *(const short8*)(Wl + ((nt * 4 + kc) * 4 + quad) * 128 + ln * 8);
            acc[0][nt] = __builtin_amdgcn_mfma_f32_16x16x32_bf16(afr[0], bfr, acc[0][nt], 0, 0, 0);
            acc[1][nt] = __builtin_amdgcn_mfma_f32_16x16x32_bf16(afr[1], bfr, acc[1][nt], 0, 0, 0);
        }
    }

#pragma unroll
    for (int mt = 0; mt < 2; ++mt)
#pragma unroll
        for (int r = 0; r < 4; ++r) {
            int row = row0 + mt * 16 + quad * 4 + r;
            if (row < N) {
#pragma unroll
                for (int nt = 0; nt < 8; ++nt)
                    Zbf[(size_t)row * NH + nt * 16 + ln] = f2bf(acc[mt][nt][r]);
            }
        }

    if (bnsum) {
#pragma unroll
        for (int nt = 0; nt < 8; ++nt) {
            float s = 0.f, q = 0.f;
#pragma unroll
            for (int mt = 0; mt < 2; ++mt)
#pragma unroll
                for (int r = 0; r < 4; ++r) {
                    int row = row0 + mt * 16 + quad * 4 + r;
                    if (row < N) { float v = acc[mt][nt][r]; s += v; q += v * v; }
                }
            s += __shfl_xor(s, 16); s += __shfl_xor(s, 32);
            q += __shfl_xor(q, 16); q += __shfl_xor(q, 32);
            if (quad == 0) {
                atomicAdd(&bnL[nt * 16 + ln], s);
                atomicAdd(&bnL[NH + nt * 16 + ln], q);
            }
        }
        __syncthreads();
        if (t < NH) {
            atomicAdd(&bnsum[t], bnL[t]);
            atomicAdd(&bnsumsq[t], bnL[NH + t]);
        }
    }
}

// ---------------- fused: BN finalize + hbf=relu(zbf*sc+sh)+hbf + pool ----------------
__global__ __launch_bounds__(256) void update_pool_kernel(
    const unsigned* __restrict__ zbfu, unsigned* __restrict__ hbfu,
    const float* __restrict__ bnsum, const float* __restrict__ bnsumsq,
    const float* __restrict__ gamma, const float* __restrict__ beta,
    float invN, const int* __restrict__ gstart, float* __restrict__ pooled) {
    int g = blockIdx.x, t = threadIdx.x;
    __shared__ float scL[NH], shL[NH];
    __shared__ float2 red[256];
    if (t < NH) {
        float mu = bnsum[t] * invN;
        float var = fmaf(bnsumsq[t], invN, -mu * mu);
        float sc = gamma[t] * rsqrtf(var + 1e-5f);
        scL[t] = sc;
        shL[t] = beta[t] - mu * sc;
    }
    __syncthreads();
    int s = gstart[g], e = gstart[g + 1];
    int c2 = t & 63, half = t >> 6;
    float2 sc = make_float2(scL[2 * c2], scL[2 * c2 + 1]);
    float2 sh = make_float2(shL[2 * c2], shL[2 * c2 + 1]);
    float2 pacc = make_float2(0.f, 0.f);
    for (int n = s + half; n < e; n += 4) {
        size_t i = (size_t)n * 64 + c2;
        unsigned zu = zbfu[i];
        unsigned hu = hbfu[i];
        float rx = fmaxf(fmaf(bflo(zu), sc.x, sh.x), 0.f) + bflo(hu);
        float ry = fmaxf(fmaf(bfhi(zu), sc.y, sh.y), 0.f) + bfhi(hu);
        hbfu[i] = packbf(rx, ry);
        pacc.x += rx; pacc.y += ry;
    }
    red[t] = pacc;
    __syncthreads();
    if (t < 64) {
        float2 a = red[t], b = red[t + 64], c = red[t + 128], d = red[t + 192];
        ((float2*)pooled)[(size_t)g * 64 + c2] =
            make_float2((a.x + b.x) + (c.x + d.x), (a.y + b.y) + (c.y + d.y));
    }
}

// ---------------- pool layer 0 (from bf16 h) ----------------
__global__ __launch_bounds__(256) void pool_kernel(
    const unsigned* __restrict__ hbfu, const int* __restrict__ gstart,
    float* __restrict__ pooled, int G) {
    int g = blockIdx.x, t = threadIdx.x;
    __shared__ float2 red[256];
    int s = gstart[g], e = gstart[g + 1];
    int c2 = t & 63, half = t >> 6;
    float2 pacc = make_float2(0.f, 0.f);
    for (int n = s + half; n < e; n += 4) {
        unsigned u = hbfu[(size_t)n * 64 + c2];
        pacc.x += bflo(u);
        pacc.y += bfhi(u);
    }
    red[t] = pacc;
    __syncthreads();
    if (t < 64) {
        float2 a = red[t], b = red[t + 64], c = red[t + 128], d = red[t + 192];
        ((float2*)pooled)[(size_t)g * 64 + c2] =
            make_float2((a.x + b.x) + (c.x + d.x), (a.y + b.y) + (c.y + d.y));
    }
}

// ---------------- JK head ----------------
__global__ void jk_kernel(const float* __restrict__ pooled, const float* __restrict__ jkW,
                          const float* __restrict__ jkb, float* __restrict__ out, int G) {
    int idx = blockIdx.x * blockDim.x + threadIdx.x;
    if (idx >= G * 10) return;
    int g = idx / 10, c = idx % 10;
    float acc = 0.f;
    for (int l = 0; l < LAYERS + 1; ++l) {
        acc += jkb[l * 10 + c];
        const float* pg = pooled + ((size_t)l * G + g) * NH;
        const float* wl = jkW + (size_t)l * NH * 10 + c;
        float s = 0.f;
#pragma unroll 16
        for (int k = 0; k < NH; ++k) s = fmaf(pg[k], wl[k * 10], s);
        acc += s;
    }
    out[idx] = acc;
}

extern "C" void kernel_launch(void* const* d_in, const int* in_sizes, int n_in,
                              void* d_out, int out_size, void* d_ws, size_t ws_size,
                              hipStream_t stream) {
    const float* h_in      = (const float*)d_in[0];
    const float* edge_attr = (const float*)d_in[1];
    const int*   edge_idx  = (const int*)d_in[2];
    const int*   batch     = (const int*)d_in[5];
    const float* emb_W     = (const float*)d_in[6];
    const float* emb_b     = (const float*)d_in[7];
    const float* conv_W    = (const float*)d_in[8];
    const float* conv_b    = (const float*)d_in[9];
    const float* conv_We   = (const float*)d_in[10];
    const float* conv_be   = (const float*)d_in[11];
    const float* bn_gamma  = (const float*)d_in[12];
    const float* bn_beta   = (const float*)d_in[13];
    const float* jk_W      = (const float*)d_in[14];
    const float* jk_b      = (const float*)d_in[15];
    float* out = (float*)d_out;

    const int N = in_sizes[0] / NH;
    const int E = in_sizes[1] / 16;
    const int G = out_size / 10;
    const int NBKT = (N + BW - 1) / BW;          // 391
    const int NCH  = (E + CHUNK - 1) / CHUNK;    // 196
    const int NTOT = NBKT * NCH;
    const int NBW  = (NTOT + 1023) / 1024;

    const int* src = edge_idx;
    const int* dst = edge_idx + E;

    size_t off = 0;
    auto alloc = [&](size_t bytes) -> void* {
        void* p = (char*)d_ws + off;
        off += (bytes + 255) & ~(size_t)255;
        return p;
    };
    unsigned short* hbf = (unsigned short*)alloc((size_t)N * NH * 2);
    unsigned short* xbf = (unsigned short*)alloc((size_t)N * NH * 2);
    unsigned short* zbf = (unsigned short*)alloc((size_t)N * NH * 2);
    unsigned short* Wsw = (unsigned short*)alloc((size_t)5 * NH * NH * 2);
    float* pooled  = (float*)alloc((size_t)(LAYERS + 1) * G * NH * 4);
    float* easum   = (float*)alloc((size_t)N * 16 * 4);
    size_t zero_off = off;
    float* bnsum   = (float*)alloc((size_t)LAYERS * NH * 4);
    float* bnsumsq = (float*)alloc((size_t)LAYERS * NH * 4);
    size_t zero_bytes = off - zero_off;
    int* gH        = (int*)alloc((size_t)(NTOT + 1) * 4);
    int* bsumW     = (int*)alloc((size_t)NBW * 4);
    int* gstart    = (int*)alloc((size_t)(G + 1) * 4);
    int* row_start = (int*)alloc((size_t)(N + 1) * 4);
    int2* bkt      = (int2*)alloc((size_t)E * 8);
    int2* pk       = (int2*)alloc((size_t)E * 8);
    (void)ws_size; (void)n_in;

    hipMemsetAsync((char*)d_ws + zero_off, 0, zero_bytes, stream);

    wswz_kernel<<<(5 * 8192 + 255) / 256, 256, 0, stream>>>(emb_W, conv_W, Wsw);

    // CSR build: block-aggregated counting sort
    bhist_kernel<<<NCH, 256, 0, stream>>>(dst, E, gH, NBKT, NCH, batch, gstart, N, G);
    block_sum_kernel<<<NBW, 256, 0, stream>>>(gH, bsumW, NTOT);
    scan_partials_kernel<<<1, 1024, 0, stream>>>(bsumW, NBW, gH, NTOT);
    local_scan_kernel<<<NBW, 256, 0, stream>>>(gH, bsumW, gH, NTOT);
    bplace_kernel<<<NCH, 256, 0, stream>>>(src, dst, E, gH, NBKT, NCH, bkt);
    bfinal_kernel<<<NBKT, 256, 0, stream>>>(bkt, gH, NCH, row_start, pk, N, E);
    easum_kernel<<<(N + 15) / 16, 256, 0, stream>>>(edge_attr, pk, row_start, easum, N);

    dim3 gemm_grid((N + 127) / 128);
    dim3 agg_grid((N + 3) / 4);

    // embedding: fp32 A path, bf16 out
    gemm_mfma_kernel<<<gemm_grid, 256, 0, stream>>>(
        nullptr, h_in, Wsw, emb_b, hbf, N, nullptr, nullptr);
    pool_kernel<<<G, 256, 0, stream>>>((const unsigned*)hbf, gstart, pooled, G);

    for (int l = 0; l < LAYERS; ++l) {
        aggregate_kernel<<<agg_grid, 256, 0, stream>>>(
            (const unsigned*)hbf, pk, row_start, easum,
            conv_We + (size_t)l * 16 * NH, conv_be + (size_t)l * NH,
            (unsigned*)xbf, N);
        gemm_mfma_kernel<<<gemm_grid, 256, 0, stream>>>(
            xbf, nullptr, Wsw + (size_t)(l + 1) * NH * NH, conv_b + (size_t)l * NH,
            zbf, N, bnsum + (size_t)l * NH, bnsumsq + (size_t)l * NH);
        update_pool_kernel<<<G, 256, 0, stream>>>(
            (const unsigned*)zbf, (unsigned*)hbf,
            bnsum + (size_t)l * NH, bnsumsq + (size_t)l * NH,
            bn_gamma + (size_t)l * NH, bn_beta + (size_t)l * NH,
            1.0f / (float)N, gstart, pooled + (size_t)(l + 1) * G * NH);
    }

    jk_kernel<<<(G * 10 + 255) / 256, 256, 0, stream>>>(pooled, jk_W, jk_b, out, G);
}

// Round 10
// 542.894 us; speedup vs baseline: 2.1545x; 1.0113x over previous
//
#include <hip/hip_runtime.h>

#define NH 128
#define LAYERS 4
#define BW 128          // nodes per CSR bucket = GEMM row tile
#define CHUNK 4096      // edges per counting-sort chunk

typedef __attribute__((ext_vector_type(8))) short short8;
typedef __attribute__((ext_vector_type(4))) float f32x4;

__device__ __forceinline__ unsigned short f2bf(float f) {
    unsigned u = __float_as_uint(f);
    u += 0x7fffu + ((u >> 16) & 1u);          // round-to-nearest-even
    return (unsigned short)(u >> 16);
}
__device__ __forceinline__ float bflo(unsigned u) { return __uint_as_float(u << 16); }
__device__ __forceinline__ float bfhi(unsigned u) { return __uint_as_float(u & 0xffff0000u); }
__device__ __forceinline__ unsigned packbf(float x, float y) {
    return (unsigned)f2bf(x) | ((unsigned)f2bf(y) << 16);
}

// ---------------- pre-swizzle 5 weight matrices to MFMA bf16 layout ------------------
__global__ void wswz_kernel(const float* __restrict__ emb_W, const float* __restrict__ conv_W,
                            unsigned short* __restrict__ Wsw) {
    int idx = blockIdx.x * 256 + threadIdx.x;   // over 5*8192 float2
    if (idx >= 5 * 8192) return;
    int m = idx >> 13, i = idx & 8191;
    const float* W = (m == 0) ? emb_W : conv_W + (size_t)(m - 1) * 16384;
    float2 w2 = ((const float2*)W)[i];
    int k = i >> 6, n = (i & 63) * 2;
    int kc = k >> 5, quad = (k >> 3) & 3, j = k & 7;
    int base = m * 16384 + (((n >> 4) * 4 + kc) * 4 + quad) * 128 + j;
    Wsw[base + ((n & 15) << 3)] = f2bf(w2.x);
    Wsw[base + (((n + 1) & 15) << 3)] = f2bf(w2.y);
}

// ---------------- phase A: per-chunk LDS bucket histogram + gstart -------------------
__global__ __launch_bounds__(256) void bhist_kernel(const int* __restrict__ dst, int E,
                                                    int* __restrict__ gH, int NBKT, int NCH,
                                                    const int* __restrict__ batch,
                                                    int* __restrict__ gstart, int N, int G) {
    __shared__ int hist[512];
    int b = blockIdx.x, t = threadIdx.x;
    for (int i = t; i < NBKT; i += 256) hist[i] = 0;
    __syncthreads();
    int base = b * CHUNK, end = min(base + CHUNK, E);
    for (int e = base + t; e < end; e += 256)
        atomicAdd(&hist[dst[e] >> 7], 1);
    __syncthreads();
    for (int i = t; i < NBKT; i += 256) gH[i * NCH + b] = hist[i];

    for (int i = b * 256 + t; i < N; i += gridDim.x * 256) {
        int bb = batch[i];
        int prev = (i == 0) ? -1 : batch[i - 1];
        for (int g = prev + 1; g <= bb; ++g) gstart[g] = i;
        if (i == N - 1)
            for (int g = bb + 1; g <= G; ++g) gstart[g] = N;
    }
}

// ---------------- hierarchical exclusive scan ----------------------------------------
__global__ __launch_bounds__(256) void block_sum_kernel(const int* __restrict__ deg,
                                                        int* __restrict__ bsum, int n) {
    __shared__ int red[256];
    int t = threadIdx.x;
    int base = blockIdx.x * 1024;
    int s = 0;
#pragma unroll
    for (int i = 0; i < 4; ++i) {
        int idx = base + i * 256 + t;
        if (idx < n) s += deg[idx];
    }
    red[t] = s;
    __syncthreads();
    for (int off = 128; off > 0; off >>= 1) {
        if (t < off) red[t] += red[t + off];
        __syncthreads();
    }
    if (t == 0) bsum[blockIdx.x] = red[0];
}

__global__ __launch_bounds__(1024) void scan_partials_kernel(int* __restrict__ bsum, int nb,
                                                             int* __restrict__ total_out, int n) {
    __shared__ int part[1024];
    int t = threadIdx.x;
    int v = (t < nb) ? bsum[t] : 0;
    part[t] = v;
    __syncthreads();
    for (int off = 1; off < 1024; off <<= 1) {
        int u = (t >= off) ? part[t - off] : 0;
        __syncthreads();
        part[t] += u;
        __syncthreads();
    }
    if (t < nb) bsum[t] = part[t] - v;
    if (t == 1023) total_out[n] = part[1023];
}

__global__ __launch_bounds__(256) void local_scan_kernel(const int* __restrict__ deg,
                                                         const int* __restrict__ bsum,
                                                         int* __restrict__ outA, int n) {
    __shared__ int part[256];
    int t = threadIdx.x;
    int base = blockIdx.x * 1024 + t * 4;
    int v0 = 0, v1 = 0, v2 = 0, v3 = 0;
    if (base + 3 < n) {
        int4 v = *(const int4*)(deg + base);
        v0 = v.x; v1 = v.y; v2 = v.z; v3 = v.w;
    } else {
        if (base + 0 < n) v0 = deg[base + 0];
        if (base + 1 < n) v1 = deg[base + 1];
        if (base + 2 < n) v2 = deg[base + 2];
        if (base + 3 < n) v3 = deg[base + 3];
    }
    int tsum = v0 + v1 + v2 + v3;
    part[t] = tsum;
    __syncthreads();
    for (int off = 1; off < 256; off <<= 1) {
        int u = (t >= off) ? part[t - off] : 0;
        __syncthreads();
        part[t] += u;
        __syncthreads();
    }
    int run = bsum[blockIdx.x] + part[t] - tsum;
    int r0 = run, r1 = run + v0, r2 = r1 + v1, r3 = r2 + v2;
    if (base + 3 < n) {
        *(int4*)(outA + base) = make_int4(r0, r1, r2, r3);
    } else {
        if (base + 0 < n) outA[base + 0] = r0;
        if (base + 1 < n) outA[base + 1] = r1;
        if (base + 2 < n) outA[base + 2] = r2;
        if (base + 3 < n) outA[base + 3] = r3;
    }
}

// ---------------- phase C: place edges into buckets (LDS cursors) --------------------
__global__ __launch_bounds__(256) void bplace_kernel(const int* __restrict__ src,
                                                     const int* __restrict__ dst, int E,
                                                     const int* __restrict__ gOff,
                                                     int NBKT, int NCH,
                                                     int2* __restrict__ bkt) {
    __shared__ int cur[512];
    int b = blockIdx.x, t = threadIdx.x;
    for (int i = t; i < NBKT; i += 256) cur[i] = gOff[i * NCH + b];
    __syncthreads();
    int base = b * CHUNK, end = min(base + CHUNK, E);
    for (int e = base + t; e < end; e += 256) {
        int d = dst[e];
        int p = atomicAdd(&cur[d >> 7], 1);
        bkt[p] = make_int2(src[e], ((d & (BW - 1)) << 25) | e);   // E < 2^25
    }
}

// ---------------- per-bucket finalize: row_start slice + ordered pk ------------------
__global__ __launch_bounds__(256) void bfinal_kernel(const int2* __restrict__ bkt,
                                                     const int* __restrict__ gOff, int NCH,
                                                     int* __restrict__ row_start,
                                                     int2* __restrict__ pk,
                                                     int N, int E) {
    __shared__ int cnt[BW], par[BW];
    int b = blockIdx.x, t = threadIdx.x;
    int s = gOff[b * NCH];
    int e = (b + 1 < (int)gridDim.x) ? gOff[(b + 1) * NCH] : E;
    if (t < BW) cnt[t] = 0;
    __syncthreads();
    for (int p = s + t; p < e; p += 256)
        atomicAdd(&cnt[(unsigned)bkt[p].y >> 25], 1);
    __syncthreads();
    if (t < BW) par[t] = cnt[t];
    __syncthreads();
    for (int off = 1; off < BW; off <<= 1) {
        int u = (t < BW && t >= off) ? par[t - off] : 0;
        __syncthreads();
        if (t < BW) par[t] += u;
        __syncthreads();
    }
    int node = b * BW + t;
    if (t < BW) {
        int excl = par[t] - cnt[t];
        if (node <= N) row_start[node] = s + excl;
        cnt[t] = s + excl;
    }
    if (b == 0 && t == 0) row_start[N] = E;
    __syncthreads();
    for (int p = s + t; p < e; p += 256) {
        int2 v = bkt[p];
        int dloc = (unsigned)v.y >> 25;
        int pos = atomicAdd(&cnt[dloc], 1);
        pk[pos] = make_int2(v.x, v.y & 0x1FFFFFF);
    }
}

// ---------------- easum ----------------
__global__ __launch_bounds__(256) void easum_kernel(const float* __restrict__ edge_attr,
                                                    const int2* __restrict__ pk,
                                                    const int* __restrict__ row_start,
                                                    float* __restrict__ easum, int N) {
    int t = threadIdx.x;
    int node = blockIdx.x * 16 + (t >> 4);
    int k = t & 15;
    if (node >= N) return;
    int rs = row_start[node], re = row_start[node + 1];
    float acc = 0.f;
    for (int p = rs; p < re; ++p)
        acc += edge_attr[(size_t)pk[p].y * 16 + k];
    easum[node * 16 + k] = acc;
}

// ---------------- fused aggregate + MFMA GEMM ----------------------------------------
// Block = 1 bucket (128 dst nodes), 512 threads = 8 waves, 16 nodes/wave.
// Gather x-rows into LDS (bank-XOR swizzle), then each wave MFMAs its own 16 rows.
// B-frags read directly from global Wsw (L1/L2-resident, 32 KB). No mid-block barrier.
__global__ __launch_bounds__(512) void agg_gemm_kernel(
    const unsigned* __restrict__ hbfu, const int2* __restrict__ pk,
    const int* __restrict__ row_start, const float* __restrict__ easum,
    const float* __restrict__ We, const float* __restrict__ be,
    const unsigned short* __restrict__ Wsw, const float* __restrict__ bias,
    unsigned short* __restrict__ Zbf, int N,
    float* __restrict__ bnsum, float* __restrict__ bnsumsq) {
    __shared__ unsigned xL[128 * 64];       // 32KB x-tile, word-swizzled
    __shared__ float2 WeL[16 * 64];         // 8KB
    __shared__ float bnL[2 * NH];           // 1KB
    int t = threadIdx.x;
    const float2* Wg2 = (const float2*)We;
    for (int i = t; i < 16 * 64; i += 512) WeL[i] = Wg2[i];
    if (t < 2 * NH) bnL[t] = 0.f;
    __syncthreads();

    int wave = t >> 6, lane = t & 63;
    int b = blockIdx.x;

    // ---- gather phase: 16 nodes per wave ----
    for (int i = 0; i < 16; ++i) {
        int nl = wave * 16 + i;
        int n = b * BW + nl;
        unsigned widx = nl * 64 + (lane ^ ((nl & 15) << 2));
        if (n >= N) { xL[widx] = 0u; continue; }
        unsigned uself = hbfu[(size_t)n * 64 + lane];
        float2 acc = make_float2(bflo(uself), bfhi(uself));
        float2 acc2 = make_float2(0.f, 0.f);
        float2 acc3 = make_float2(0.f, 0.f);
        float2 acc4 = make_float2(0.f, 0.f);
        int rs = row_start[n], re = row_start[n + 1];
        float myea = (lane < 16) ? easum[n * 16 + lane] : 0.f;

        for (int base = rs; base < re; base += 64) {
            int cnt = min(64, re - base);
            int myS = (base + lane < re) ? pk[base + lane].x : 0;
            int j = 0;
            for (; j + 15 < cnt; j += 16) {
                int s0 = __shfl(myS, j);      int s1 = __shfl(myS, j + 1);
                int s2 = __shfl(myS, j + 2);  int s3 = __shfl(myS, j + 3);
                int s4 = __shfl(myS, j + 4);  int s5 = __shfl(myS, j + 5);
                int s6 = __shfl(myS, j + 6);  int s7 = __shfl(myS, j + 7);
                int s8 = __shfl(myS, j + 8);  int s9 = __shfl(myS, j + 9);
                int sa = __shfl(myS, j + 10); int sb = __shfl(myS, j + 11);
                int sc = __shfl(myS, j + 12); int sd = __shfl(myS, j + 13);
                int se = __shfl(myS, j + 14); int sf = __shfl(myS, j + 15);
                unsigned u0 = hbfu[(size_t)s0 * 64 + lane];
                unsigned u1 = hbfu[(size_t)s1 * 64 + lane];
                unsigned u2 = hbfu[(size_t)s2 * 64 + lane];
                unsigned u3 = hbfu[(size_t)s3 * 64 + lane];
                unsigned u4 = hbfu[(size_t)s4 * 64 + lane];
                unsigned u5 = hbfu[(size_t)s5 * 64 + lane];
                unsigned u6 = hbfu[(size_t)s6 * 64 + lane];
                unsigned u7 = hbfu[(size_t)s7 * 64 + lane];
                unsigned u8 = hbfu[(size_t)s8 * 64 + lane];
                unsigned u9 = hbfu[(size_t)s9 * 64 + lane];
                unsigned ua = hbfu[(size_t)sa * 64 + lane];
                unsigned ub = hbfu[(size_t)sb * 64 + lane];
                unsigned uc = hbfu[(size_t)sc * 64 + lane];
                unsigned ud = hbfu[(size_t)sd * 64 + lane];
                unsigned ue = hbfu[(size_t)se * 64 + lane];
                unsigned uf = hbfu[(size_t)sf * 64 + lane];
                acc.x  += bflo(u0) + bflo(u1) + bflo(u2) + bflo(u3);
                acc.y  += bfhi(u0) + bfhi(u1) + bfhi(u2) + bfhi(u3);
                acc2.x += bflo(u4) + bflo(u5) + bflo(u6) + bflo(u7);
                acc2.y += bfhi(u4) + bfhi(u5) + bfhi(u6) + bfhi(u7);
                acc3.x += bflo(u8) + bflo(u9) + bflo(ua) + bflo(ub);
                acc3.y += bfhi(u8) + bfhi(u9) + bfhi(ua) + bfhi(ub);
                acc4.x += bflo(uc) + bflo(ud) + bflo(ue) + bflo(uf);
                acc4.y += bfhi(uc) + bfhi(ud) + bfhi(ue) + bfhi(uf);
            }
            for (; j + 3 < cnt; j += 4) {
                int s0 = __shfl(myS, j);
                int s1 = __shfl(myS, j + 1);
                int s2 = __shfl(myS, j + 2);
                int s3 = __shfl(myS, j + 3);
                unsigned u0 = hbfu[(size_t)s0 * 64 + lane];
                unsigned u1 = hbfu[(size_t)s1 * 64 + lane];
                unsigned u2 = hbfu[(size_t)s2 * 64 + lane];
                unsigned u3 = hbfu[(size_t)s3 * 64 + lane];
                acc.x += bflo(u0) + bflo(u1) + bflo(u2) + bflo(u3);
                acc.y += bfhi(u0) + bfhi(u1) + bfhi(u2) + bfhi(u3);
            }
            for (; j < cnt; ++j) {
                int s = __shfl(myS, j);
                unsigned u = hbfu[(size_t)s * 64 + lane];
                acc.x += bflo(u);
                acc.y += bfhi(u);
            }
        }
        acc.x += (acc2.x + acc3.x) + acc4.x;
        acc.y += (acc2.y + acc3.y) + acc4.y;

        float degf = (float)(re - rs);
        float2 be2 = ((const float2*)be)[lane];
#pragma unroll
        for (int k = 0; k < 16; ++k) {
            float e = __shfl(myea, k);
            float2 w = WeL[k * 64 + lane];
            acc.x = fmaf(e, w.x, acc.x);
            acc.y = fmaf(e, w.y, acc.y);
        }
        acc.x += degf * be2.x;
        acc.y += degf * be2.y;
        xL[widx] = packbf(acc.x, acc.y);
    }

    // ---- GEMM phase: wave consumes its own 16 rows (no cross-wave dep, no barrier) --
    int quad = lane >> 4, ln = lane & 15;
    int ar = wave * 16 + ln;                 // A row within tile
    f32x4 acc[8];
#pragma unroll
    for (int nt = 0; nt < 8; ++nt) {
        float bv = bias[nt * 16 + ln];
        acc[nt] = (f32x4){bv, bv, bv, bv};
    }
#pragma unroll
    for (int kc = 0; kc < 4; ++kc) {
        int widx = ar * 64 + ((kc * 16 + quad * 4) ^ ((ar & 15) << 2));
        short8 afr = *(const short8*)(xL + widx);
#pragma unroll
        for (int nt = 0; nt < 8; ++nt) {
            short8 bfr = *(const short8*)(Wsw + ((nt * 4 + kc) * 4 + quad) * 128 + ln * 8);
            acc[nt] = __builtin_amdgcn_mfma_f32_16x16x32_bf16(afr, bfr, acc[nt], 0, 0, 0);
        }
    }

#pragma unroll
    for (int r = 0; r < 4; ++r) {
        int row = b * BW + wave * 16 + quad * 4 + r;
        if (row < N) {
#pragma unroll
            for (int nt = 0; nt < 8; ++nt)
                Zbf[(size_t)row * NH + nt * 16 + ln] = f2bf(acc[nt][r]);
        }
    }

    // BN column stats
#pragma unroll
    for (int nt = 0; nt < 8; ++nt) {
        float s = 0.f, q = 0.f;
#pragma unroll
        for (int r = 0; r < 4; ++r) {
            int row = b * BW + wave * 16 + quad * 4 + r;
            if (row < N) { float v = acc[nt][r]; s += v; q += v * v; }
        }
        s += __shfl_xor(s, 16); s += __shfl_xor(s, 32);
        q += __shfl_xor(q, 16); q += __shfl_xor(q, 32);
        if (quad == 0) {
            atomicAdd(&bnL[nt * 16 + ln], s);
            atomicAdd(&bnL[NH + nt * 16 + ln], q);
        }
    }
    __syncthreads();
    if (t < NH) {
        atomicAdd(&bnsum[t], bnL[t]);
        atomicAdd(&bnsumsq[t], bnL[NH + t]);
    }
}

// ---------------- MFMA GEMM (embed layer only): hbf = bf16(h_in @ W + b) -------------
__global__ __launch_bounds__(256) void gemm_mfma_kernel(
    const float* __restrict__ Af32, const unsigned short* __restrict__ Wsw,
    const float* __restrict__ bias, unsigned short* __restrict__ Zbf, int N) {
    __shared__ unsigned short Wl[128 * 128];
    int t = threadIdx.x;
    {
        const float4* Wg = (const float4*)Wsw;
        float4* Wl4 = (float4*)Wl;
        for (int i = t; i < 2048; i += 256) Wl4[i] = Wg[i];
    }
    __syncthreads();

    int wave = t >> 6, lane = t & 63;
    int quad = lane >> 4, ln = lane & 15;
    int row0 = blockIdx.x * 128 + wave * 32;

    f32x4 acc[2][8];
#pragma unroll
    for (int nt = 0; nt < 8; ++nt) {
        float bv = bias[nt * 16 + ln];
        acc[0][nt] = (f32x4){bv, bv, bv, bv};
        acc[1][nt] = (f32x4){bv, bv, bv, bv};
    }

    for (int kc = 0; kc < 4; ++kc) {
        short8 afr[2];
#pragma unroll
        for (int mt = 0; mt < 2; ++mt) {
            int ar = row0 + mt * 16 + ln; if (ar >= N) ar = N - 1;
            const float4* ap = (const float4*)(Af32 + (size_t)ar * NH + kc * 32 + quad * 8);
            float4 a0 = ap[0], a1 = ap[1];
            short8 v;
            v[0] = (short)f2bf(a0.x); v[1] = (short)f2bf(a0.y);
            v[2] = (short)f2bf(a0.z); v[3] = (short)f2bf(a0.w);
            v[4] = (short)f2bf(a1.x); v[5] = (short)f2bf(a1.y);
            v[6] = (short)f2bf(a1.z); v[7] = (short)f2bf(a1.w);
            afr[mt] = v;
        }
#pragma unroll
        for (int nt = 0; nt < 8; ++nt) {
            short8 bfr = *(const short8*)(Wl + ((nt * 4 + kc) * 4 + quad) * 128 + ln * 8);
            acc[0][nt] = __builtin_amdgcn_mfma_f32_16x16x32_bf16(afr[0], bfr, acc[0][nt], 0, 0, 0);
            acc[1][nt] = __builtin_amdgcn_mfma_f32_16x16x32_bf16(afr[1], bfr, acc[1][nt], 0, 0, 0);
        }
    }

#pragma unroll
    for (int mt = 0; mt < 2; ++mt)
#pragma unroll
        for (int r = 0; r < 4; ++r) {
            int row = row0 + mt * 16 + quad * 4 + r;
            if (row < N) {
#pragma unroll
                for (int nt = 0; nt < 8; ++nt)
                    Zbf[(size_t)row * NH + nt * 16 + ln] = f2bf(acc[mt][nt][r]);
            }
        }
}

// ---------------- fused: BN finalize + hbf=relu(zbf*sc+sh)+hbf + pool ----------------
__global__ __launch_bounds__(256) void update_pool_kernel(
    const unsigned* __restrict__ zbfu, unsigned* __restrict__ hbfu,
    const float* __restrict__ bnsum, const float* __restrict__ bnsumsq,
    const float* __restrict__ gamma, const float* __restrict__ beta,
    float invN, const int* __restrict__ gstart, float* __restrict__ pooled) {
    int g = blockIdx.x, t = threadIdx.x;
    __shared__ float scL[NH], shL[NH];
    __shared__ float2 red[256];
    if (t < NH) {
        float mu = bnsum[t] * invN;
        float var = fmaf(bnsumsq[t], invN, -mu * mu);
        float sc = gamma[t] * rsqrtf(var + 1e-5f);
        scL[t] = sc;
        shL[t] = beta[t] - mu * sc;
    }
    __syncthreads();
    int s = gstart[g], e = gstart[g + 1];
    int c2 = t & 63, half = t >> 6;
    float2 sc = make_float2(scL[2 * c2], scL[2 * c2 + 1]);
    float2 sh = make_float2(shL[2 * c2], shL[2 * c2 + 1]);
    float2 pacc = make_float2(0.f, 0.f);
    for (int n = s + half; n < e; n += 4) {
        size_t i = (size_t)n * 64 + c2;
        unsigned zu = zbfu[i];
        unsigned hu = hbfu[i];
        float rx = fmaxf(fmaf(bflo(zu), sc.x, sh.x), 0.f) + bflo(hu);
        float ry = fmaxf(fmaf(bfhi(zu), sc.y, sh.y), 0.f) + bfhi(hu);
        hbfu[i] = packbf(rx, ry);
        pacc.x += rx; pacc.y += ry;
    }
    red[t] = pacc;
    __syncthreads();
    if (t < 64) {
        float2 a = red[t], b = red[t + 64], c = red[t + 128], d = red[t + 192];
        ((float2*)pooled)[(size_t)g * 64 + c2] =
            make_float2((a.x + b.x) + (c.x + d.x), (a.y + b.y) + (c.y + d.y));
    }
}

// ---------------- pool layer 0 (bf16 h) ----------------
__global__ __launch_bounds__(256) void pool_kernel(
    const unsigned* __restrict__ hbfu, const int* __restrict__ gstart,
    float* __restrict__ pooled, int G) {
    int g = blockIdx.x, t = threadIdx.x;
    __shared__ float2 red[256];
    int s = gstart[g], e = gstart[g + 1];
    int c2 = t & 63, half = t >> 6;
    float2 pacc = make_float2(0.f, 0.f);
    for (int n = s + half; n < e; n += 4) {
        unsigned u = hbfu[(size_t)n * 64 + c2];
        pacc.x += bflo(u);
        pacc.y += bfhi(u);
    }
    red[t] = pacc;
    __syncthreads();
    if (t < 64) {
        float2 a = red[t], b = red[t + 64], c = red[t + 128], d = red[t + 192];
        ((float2*)pooled)[(size_t)g * 64 + c2] =
            make_float2((a.x + b.x) + (c.x + d.x), (a.y + b.y) + (c.y + d.y));
    }
}

// ---------------- JK head ----------------
__global__ void jk_kernel(const float* __restrict__ pooled, const float* __restrict__ jkW,
                          const float* __restrict__ jkb, float* __restrict__ out, int G) {
    int idx = blockIdx.x * blockDim.x + threadIdx.x;
    if (idx >= G * 10) return;
    int g = idx / 10, c = idx % 10;
    float acc = 0.f;
    for (int l = 0; l < LAYERS + 1; ++l) {
        acc += jkb[l * 10 + c];
        const float* pg = pooled + ((size_t)l * G + g) * NH;
        const float* wl = jkW + (size_t)l * NH * 10 + c;
        float s = 0.f;
#pragma unroll 16
        for (int k = 0; k < NH; ++k) s = fmaf(pg[k], wl[k * 10], s);
        acc += s;
    }
    out[idx] = acc;
}

extern "C" void kernel_launch(void* const* d_in, const int* in_sizes, int n_in,
                              void* d_out, int out_size, void* d_ws, size_t ws_size,
                              hipStream_t stream) {
    const float* h_in      = (const float*)d_in[0];
    const float* edge_attr = (const float*)d_in[1];
    const int*   edge_idx  = (const int*)d_in[2];
    const int*   batch     = (const int*)d_in[5];
    const float* emb_W     = (const float*)d_in[6];
    const float* emb_b     = (const float*)d_in[7];
    const float* conv_W    = (const float*)d_in[8];
    const float* conv_b    = (const float*)d_in[9];
    const float* conv_We   = (const float*)d_in[10];
    const float* conv_be   = (const float*)d_in[11];
    const float* bn_gamma  = (const float*)d_in[12];
    const float* bn_beta   = (const float*)d_in[13];
    const float* jk_W      = (const float*)d_in[14];
    const float* jk_b      = (const float*)d_in[15];
    float* out = (float*)d_out;

    const int N = in_sizes[0] / NH;
    const int E = in_sizes[1] / 16;
    const int G = out_size / 10;
    const int NBKT = (N + BW - 1) / BW;          // 391
    const int NCH  = (E + CHUNK - 1) / CHUNK;    // 196
    const int NTOT = NBKT * NCH;
    const int NBW  = (NTOT + 1023) / 1024;

    const int* src = edge_idx;
    const int* dst = edge_idx + E;

    size_t off = 0;
    auto alloc = [&](size_t bytes) -> void* {
        void* p = (char*)d_ws + off;
        off += (bytes + 255) & ~(size_t)255;
        return p;
    };
    unsigned short* hbf = (unsigned short*)alloc((size_t)N * NH * 2);
    unsigned short* zbf = (unsigned short*)alloc((size_t)N * NH * 2);
    unsigned short* Wsw = (unsigned short*)alloc((size_t)5 * NH * NH * 2);
    float* pooled  = (float*)alloc((size_t)(LAYERS + 1) * G * NH * 4);
    float* easum   = (float*)alloc((size_t)N * 16 * 4);
    size_t zero_off = off;
    float* bnsum   = (float*)alloc((size_t)LAYERS * NH * 4);
    float* bnsumsq = (float*)alloc((size_t)LAYERS * NH * 4);
    size_t zero_bytes = off - zero_off;
    int* gH        = (int*)alloc((size_t)(NTOT + 1) * 4);
    int* bsumW     = (int*)alloc((size_t)NBW * 4);
    int* gstart    = (int*)alloc((size_t)(G + 1) * 4);
    int* row_start = (int*)alloc((size_t)(N + 1) * 4);
    int2* bkt      = (int2*)alloc((size_t)E * 8);
    int2* pk       = (int2*)alloc((size_t)E * 8);
    (void)ws_size; (void)n_in;

    hipMemsetAsync((char*)d_ws + zero_off, 0, zero_bytes, stream);

    wswz_kernel<<<(5 * 8192 + 255) / 256, 256, 0, stream>>>(emb_W, conv_W, Wsw);

    // CSR build: block-aggregated counting sort
    bhist_kernel<<<NCH, 256, 0, stream>>>(dst, E, gH, NBKT, NCH, batch, gstart, N, G);
    block_sum_kernel<<<NBW, 256, 0, stream>>>(gH, bsumW, NTOT);
    scan_partials_kernel<<<1, 1024, 0, stream>>>(bsumW, NBW, gH, NTOT);
    local_scan_kernel<<<NBW, 256, 0, stream>>>(gH, bsumW, gH, NTOT);
    bplace_kernel<<<NCH, 256, 0, stream>>>(src, dst, E, gH, NBKT, NCH, bkt);
    bfinal_kernel<<<NBKT, 256, 0, stream>>>(bkt, gH, NCH, row_start, pk, N, E);
    easum_kernel<<<(N + 15) / 16, 256, 0, stream>>>(edge_attr, pk, row_start, easum, N);

    // embedding
    gemm_mfma_kernel<<<NBKT, 256, 0, stream>>>(h_in, Wsw, emb_b, hbf, N);
    pool_kernel<<<G, 256, 0, stream>>>((const unsigned*)hbf, gstart, pooled, G);

    for (int l = 0; l < LAYERS; ++l) {
        agg_gemm_kernel<<<NBKT, 512, 0, stream>>>(
            (const unsigned*)hbf, pk, row_start, easum,
            conv_We + (size_t)l * 16 * NH, conv_be + (size_t)l * NH,
            Wsw + (size_t)(l + 1) * NH * NH, conv_b + (size_t)l * NH,
            zbf, N, bnsum + (size_t)l * NH, bnsumsq + (size_t)l * NH);
        update_pool_kernel<<<G, 256, 0, stream>>>(
            (const unsigned*)zbf, (unsigned*)hbf,
            bnsum + (size_t)l * NH, bnsumsq + (size_t)l * NH,
            bn_gamma + (size_t)l * NH, bn_beta + (size_t)l * NH,
            1.0f / (float)N, gstart, pooled + (size_t)(l + 1) * G * NH);
    }

    jk_kernel<<<(G * 10 + 255) / 256, 256, 0, stream>>>(pooled, jk_W, jk_b, out, G);
}